// Round 16
// baseline (124.730 us; speedup 1.0000x reference)
//
#include <hip/hip_runtime.h>
#include <stdint.h>

// TopoLoss: approximate persistence-diagram Wasserstein loss.
// Round 16: (1) type-split scan: each wave computes ONLY minima or ONLY maxima
// of its 16 rows (32 waves/image) -> half the per-wave VALU, 2x waves for
// latency hiding; segment layout identical to proven r14/15. (2) sel kernel is
// per-SAMPLE with the loss fused in LDS (no diag round-trip, 3 kernels total).
// Order statistics bit-exact.

#define KPTS 128
#define BIGF 1.0e9f
#define IMG_W 256
#define NPIX (IMG_W * IMG_W)
#define NTH 1024
#define QITERS (NPIX / 4 / NTH)   // fallback kernel
#define SEGC 1024                 // per-wave segment capacity (E~819, sigma~26: +8sig)
#define LCAP (16 * SEGC)          // 16384 per image-type
#define HPAD 264                  // histogram copy stride (bank-skew: 264%32=8)

__device__ __forceinline__ uint32_t f2key(float f) {
    uint32_t u = __float_as_uint(f);
    return (u & 0x80000000u) ? ~u : (u | 0x80000000u);
}
__device__ __forceinline__ float key2f(uint32_t k) {
    uint32_t u = (k & 0x80000000u) ? (k ^ 0x80000000u) : ~k;
    return __uint_as_float(u);
}

// buf layout: 0=b0 (min,low,asc) 1=d0 (max,low,asc) 2=b1 (max,high,desc) 3=d1 (min,high,desc)

// ---- rolling-window single-type segment scan: 16 rows, one extrema type ----
template <bool ISMAX>
__device__ __forceinline__ uint32_t scanSegT(const float* __restrict__ base0, int r0, int lane,
                                             unsigned long long ltm, uint32_t* __restrict__ dst) {
    uint32_t cnt = 0;
    float4 cur  = *(const float4*)(base0);
    float4 prev = (r0 > 0) ? *(const float4*)(base0 - IMG_W) : cur;   // consumed under hu guard
    float4 next = *(const float4*)(base0 + IMG_W);                    // r0+1 <= 241 < 256 always
    for (int it = 0; it < 16; ++it) {
        const int row = r0 + it;
        const bool hu = row > 0, hd = row < (IMG_W - 1);
        float4 nxt2 = cur;
        if (it < 15 && row + 2 < IMG_W)
            nxt2 = *(const float4*)(base0 + (it + 2) * IMG_W);
        float lft = __shfl_up(cur.w, 1);
        float rgt = __shfl_down(cur.x, 1);
        bool hl = (lane > 0), hr = (lane < 63);
        float cv[4] = {cur.x, cur.y, cur.z, cur.w};
        float uv[4] = {prev.x, prev.y, prev.z, prev.w};
        float dv[4] = {next.x, next.y, next.z, next.w};
        bool fl[4]; uint32_t kk[4];
        #pragma unroll
        for (int j = 0; j < 4; ++j) {
            float v = cv[j];
            bool el = (j > 0) || hl, er = (j < 3) || hr;
            float vl = (j > 0) ? cv[j - 1] : lft;
            float vr = (j < 3) ? cv[j + 1] : rgt;
            if (ISMAX) {
                float nmx = fmaxf(fmaxf(el ? vl : -BIGF, er ? vr : -BIGF),
                                  fmaxf(hu ? uv[j] : -BIGF, hd ? dv[j] : -BIGF));
                fl[j] = (v >= nmx);
            } else {
                float nmn = fminf(fminf(el ? vl : BIGF, er ? vr : BIGF),
                                  fminf(hu ? uv[j] : BIGF, hd ? dv[j] : BIGF));
                fl[j] = (v <= nmn);
            }
            kk[j] = f2key(v);
        }
        unsigned long long m0 = __ballot(fl[0]), m1 = __ballot(fl[1]),
                           m2 = __ballot(fl[2]), m3 = __ballot(fl[3]);
        uint32_t c0 = (uint32_t)__popcll(m0), c1 = (uint32_t)__popcll(m1),
                 c2 = (uint32_t)__popcll(m2), c3 = (uint32_t)__popcll(m3);
        uint32_t o;
        if (fl[0]) { o = cnt + (uint32_t)__popcll(m0 & ltm);                if (o < SEGC) dst[o] = kk[0]; }
        if (fl[1]) { o = cnt + c0 + (uint32_t)__popcll(m1 & ltm);           if (o < SEGC) dst[o] = kk[1]; }
        if (fl[2]) { o = cnt + c0 + c1 + (uint32_t)__popcll(m2 & ltm);      if (o < SEGC) dst[o] = kk[2]; }
        if (fl[3]) { o = cnt + c0 + c1 + c2 + (uint32_t)__popcll(m3 & ltm); if (o < SEGC) dst[o] = kk[3]; }
        cnt += c0 + c1 + c2 + c3;
        prev = cur; cur = next; next = nxt2;
    }
    return cnt;
}

// ---------------- K1: type-split scan (32 waves/image), zero atomics ----------------
__global__ __launch_bounds__(256) void topo_scan6_kernel(
        const float* __restrict__ X, const float* __restrict__ Y,
        uint32_t* __restrict__ gkeys, uint32_t* __restrict__ gcnt16, int B) {
    const int tid = threadIdx.x;
    const int lane = tid & 63;
    const int wv = tid >> 6;
    const int gw = blockIdx.x * 4 + wv;      // 0..2B*32-1
    const int im = gw >> 5;                  // image id (32 waves/image)
    const int type = (gw >> 4) & 1;          // 0=min, 1=max
    const int seg = gw & 15;
    const int r0 = seg * 16;
    const float* img = ((im & 1) ? Y : X) + (size_t)(im >> 1) * NPIX;
    const float* base0 = img + (size_t)r0 * IMG_W + lane * 4;
    const unsigned long long ltm = (1ull << lane) - 1ull;

    uint32_t* dst = gkeys + (size_t)(im * 2 + type) * LCAP + seg * SEGC;
    uint32_t cnt = type ? scanSegT<true>(base0, r0, lane, ltm, dst)
                        : scanSegT<false>(base0, r0, lane, ltm, dst);
    if (lane == 0)
        gcnt16[(im * 2 + type) * 16 + seg] = (cnt < SEGC) ? cnt : SEGC;
}

// ---------------- K2: per-sample radix select + register sort + fused loss ----------------
struct SMR {
    uint32_t keys[LCAP];      // 64 KB
    uint32_t h8[8 * HPAD];    // 8.25 KB (skewed copies)
    uint32_t pref[2], rank[2], ccnt[2];
    int      flagAll[2];
    float    buf[4][KPTS];    // 2 KB
    float    res[2][4][KPTS]; // 4 KB : x and y diagrams
    float    lred[2];
};                            // ~78.5 KB -> 2 blocks/CU

__device__ __forceinline__ void binSelP(const uint32_t* h, int ncop, int lane, uint32_t r,
                                        uint32_t& bsel, uint32_t& newr) {
    uint32_t b0 = 0, b1 = 0, b2 = 0, b3 = 0;
    for (int c = 0; c < ncop; ++c) {
        const uint32_t* hh = h + c * HPAD;
        b0 += hh[4 * lane];     b1 += hh[4 * lane + 1];
        b2 += hh[4 * lane + 2]; b3 += hh[4 * lane + 3];
    }
    uint32_t s4 = b0 + b1 + b2 + b3, cum = s4;
    #pragma unroll
    for (int d = 1; d < 64; d <<= 1) { uint32_t t = __shfl_up(cum, d); if (lane >= d) cum += t; }
    unsigned long long m = __ballot(cum > r);
    int L = (m == 0ull) ? 63 : __builtin_ctzll(m);
    uint32_t cumL = __shfl(cum, L), s4L = __shfl(s4, L);
    uint32_t a0 = __shfl(b0, L), a1 = __shfl(b1, L), a2 = __shfl(b2, L);
    uint32_t excl = cumL - s4L;
    if (excl + a0 > r)                { bsel = 4u * L;     newr = r - excl; }
    else if (excl + a0 + a1 > r)      { bsel = 4u * L + 1; newr = r - excl - a0; }
    else if (excl + a0 + a1 + a2 > r) { bsel = 4u * L + 2; newr = r - excl - a0 - a1; }
    else                              { bsel = 4u * L + 3; newr = r - excl - a0 - a1 - a2; }
}

// 128-element bitonic sort in registers, one wave, 2 elems/lane.
__device__ __forceinline__ void waveSort128(float e[2], bool asc, int lane) {
    for (int size = 2; size <= 128; size <<= 1) {
        for (int stride = size >> 1; stride > 0; stride >>= 1) {
            if (stride == 64) {
                float a = e[0], b = e[1];
                e[0] = asc ? fminf(a, b) : fmaxf(a, b);
                e[1] = asc ? fmaxf(a, b) : fminf(a, b);
            } else {
                #pragma unroll
                for (int r = 0; r < 2; ++r) {
                    int i = r * 64 + lane;
                    float v = e[r];
                    float w = __shfl_xor(v, stride);
                    bool up = ((i & size) == 0) ? asc : !asc;
                    bool lower = (i & stride) == 0;
                    float mn = fminf(v, w), mx = fmaxf(v, w);
                    e[r] = (lower == up) ? mn : mx;
                }
            }
        }
    }
}

__global__ __launch_bounds__(NTH, 8) void topo_sel3_kernel(
        const uint32_t* __restrict__ gkeys, const uint32_t* __restrict__ gcnt16,
        float* __restrict__ lossOut, int B) {
    __shared__ SMR sm;
    const int tid = threadIdx.x;
    const int lane = tid & 63;
    const int wv = tid >> 6;        // 16 waves
    const int s = blockIdx.x;       // sample
    const int hc = lane & 7;

    for (int half = 0; half < 2; ++half) {   // 0: x image, 1: y image
        const int imgIdx = 2 * s + half;
        for (int ph = 0; ph < 2; ++ph) {     // 0: minima -> {b0,d1}; 1: maxima -> {d0,b1}
            for (int i = tid; i < 8 * HPAD; i += NTH) sm.h8[i] = 0u;
            __syncthreads();
            const uint32_t* list = gkeys + (size_t)(imgIdx * 2 + ph) * LCAP;
            const uint32_t* cnts = gcnt16 + (imgIdx * 2 + ph) * 16;

            // every wave: 16 segment counts, shfl prefix -> my offset / total
            uint32_t cw = (lane < 16) ? cnts[lane] : 0;
            uint32_t inc = cw;
            #pragma unroll
            for (int d = 1; d < 16; d <<= 1) { uint32_t t = __shfl_up(inc, d); if (lane >= d) inc += t; }
            uint32_t C = __shfl(inc, 15);
            uint32_t myCnt = __shfl(cw, wv);
            uint32_t myOff = __shfl(inc, wv) - myCnt;

            // wave wv compacts segment wv into LDS (+ lane-privatized skewed MSB hist)
            for (uint32_t i = lane; i < myCnt; i += 64) {
                uint32_t k = list[wv * SEGC + i];
                sm.keys[myOff + i] = k;
                atomicAdd(&sm.h8[hc * HPAD + (k >> 24)], 1u);
            }
            __syncthreads();

            // top-level select: wave0 = low sel, wave1 = high sel
            if (wv < 2) {
                bool low = (wv == 0);
                if (C < KPTS) {
                    if (lane == 0) { sm.flagAll[wv] = 1; sm.pref[wv] = 0u; sm.rank[wv] = 0u; }
                } else {
                    uint32_t bsel, nr;
                    binSelP(sm.h8, 8, lane, low ? (KPTS - 1) : (C - KPTS), bsel, nr);
                    if (lane == 0) { sm.flagAll[wv] = 0; sm.pref[wv] = bsel; sm.rank[wv] = nr; }
                }
            }
            __syncthreads();

            // levels 2..0: prefix-filtered LDS list scans
            for (int lvl = 2; lvl >= 0; --lvl) {
                for (int i = tid; i < 2 * HPAD; i += NTH) sm.h8[i] = 0u;
                __syncthreads();
                int f0 = sm.flagAll[0], f1 = sm.flagAll[1];
                uint32_t p0 = sm.pref[0], p1 = sm.pref[1];
                const int sp = 8 * (lvl + 1), sb = 8 * lvl;
                for (uint32_t i = tid; i < C; i += NTH) {
                    uint32_t k = sm.keys[i], hi = k >> sp, by = (k >> sb) & 255u;
                    if (!f0 && hi == p0) atomicAdd(&sm.h8[by], 1u);
                    if (!f1 && hi == p1) atomicAdd(&sm.h8[HPAD + by], 1u);
                }
                __syncthreads();
                if (wv < 2 && !sm.flagAll[wv]) {
                    uint32_t bsel, nr;
                    binSelP(&sm.h8[wv * HPAD], 1, lane, sm.rank[wv], bsel, nr);
                    if (lane == 0) { sm.pref[wv] = (sm.pref[wv] << 8) | bsel; sm.rank[wv] = nr; }
                }
                __syncthreads();
            }

            // collect strict winners, tie/sentinel pad
            if (tid < 2) sm.ccnt[tid] = 0u;
            __syncthreads();
            const int g0 = (ph == 0) ? 0 : 1;
            const int g1 = (ph == 0) ? 3 : 2;
            {
                int f0 = sm.flagAll[0], f1 = sm.flagAll[1];
                uint32_t t0 = sm.pref[0], t1 = sm.pref[1];
                for (uint32_t i = tid; i < C; i += NTH) {
                    uint32_t k = sm.keys[i];
                    if (f0 || k < t0) { uint32_t q = atomicAdd(&sm.ccnt[0], 1u); if (q < KPTS) sm.buf[g0][q] = key2f(k); }
                    if (f1 || k > t1) { uint32_t q = atomicAdd(&sm.ccnt[1], 1u); if (q < KPTS) sm.buf[g1][q] = key2f(k); }
                }
            }
            __syncthreads();
            if (tid < 2 * KPTS) {
                int l = tid >> 7, i = tid & 127;
                int g = (l == 0) ? g0 : g1;
                if ((uint32_t)i >= sm.ccnt[l])
                    sm.buf[g][i] = sm.flagAll[l] ? ((l == 0) ? BIGF : -BIGF) : key2f(sm.pref[l]);
            }
            __syncthreads();
        }

        // 4 register sorts -> res[half]
        if (wv < 4) {
            float e[2];
            e[0] = sm.buf[wv][lane];
            e[1] = sm.buf[wv][lane + 64];
            waveSort128(e, wv < 2, lane);
            sm.res[half][wv][lane]      = e[0];
            sm.res[half][wv][lane + 64] = e[1];
        }
        __syncthreads();
    }

    // ---- fused per-slot loss ----
    float total = 0.f;
    if (tid < KPTS) {
        int i = tid;
        const float H = 0.5f * BIGF;
        float b0x = sm.res[0][0][i], d0x = sm.res[0][1][i], b1x = sm.res[0][2][i], d1x = sm.res[0][3][i];
        float b0y = sm.res[1][0][i], d0y = sm.res[1][1][i], b1y = sm.res[1][2][i], d1y = sm.res[1][3][i];
        bool vx0 = (b0x < H) && (d0x < H);
        float px0b = vx0 ? b0x : 0.f, px0d = vx0 ? fmaxf(d0x, b0x) : 0.f;
        bool vy0 = (b0y < H) && (d0y < H);
        float py0b = vy0 ? b0y : 0.f, py0d = vy0 ? fmaxf(d0y, b0y) : 0.f;
        bool vx1 = (b1x > -H) && (d1x > -H);
        float px1b = vx1 ? b1x : 0.f, px1d = vx1 ? fminf(d1x, b1x) : 0.f;
        bool vy1 = (b1y > -H) && (d1y > -H);
        float py1b = vy1 ? b1y : 0.f, py1d = vy1 ? fminf(d1y, b1y) : 0.f;
        float e0 = px0b - py0b, e1 = px0d - py0d, e2 = px1b - py1b, e3 = px1d - py1d;
        total = e0 * e0 + e1 * e1 + e2 * e2 + e3 * e3;
    }
    for (int off = 32; off; off >>= 1) total += __shfl_down(total, off);
    if (tid == 0)  sm.lred[0] = total;
    if (tid == 64) sm.lred[1] = total;
    __syncthreads();
    if (tid == 0) lossOut[s] = sm.lred[0] + sm.lred[1];
}

__global__ void topo_reduce_kernel(const float* __restrict__ ws, float* __restrict__ out, int B) {
    float v = 0.f;
    for (int i = threadIdx.x; i < B; i += 256) v += ws[i];
    __shared__ float r[4];
    for (int off = 32; off; off >>= 1) v += __shfl_down(v, off);
    if ((threadIdx.x & 63) == 0) r[threadIdx.x >> 6] = v;
    __syncthreads();
    if (threadIdx.x == 0) out[0] = (r[0] + r[1] + r[2] + r[3]) / (float)B;
}

// ================= fallback: fused pd3 kernel (round-8/9 proven) =================
template <bool WANTK>
__device__ __forceinline__ void stencilRow(const float* __restrict__ img, int row, int lane,
                                           bool mnf[4], bool mxf[4], uint32_t kk[4]) {
    const float* base = img + (size_t)row * IMG_W;
    float4 cur = *(const float4*)(base + lane * 4);
    bool hu = row > 0, hd = row < (IMG_W - 1);
    float4 up = cur, dn = cur;
    if (hu) up = *(const float4*)(base - IMG_W + lane * 4);
    if (hd) dn = *(const float4*)(base + IMG_W + lane * 4);
    float lft = __shfl_up(cur.w, 1);
    float rgt = __shfl_down(cur.x, 1);
    bool hl = (lane > 0), hr = (lane < 63);
    float cv[4] = {cur.x, cur.y, cur.z, cur.w};
    float uv[4] = {up.x, up.y, up.z, up.w};
    float dv[4] = {dn.x, dn.y, dn.z, dn.w};
    #pragma unroll
    for (int j = 0; j < 4; ++j) {
        float v = cv[j];
        bool el = (j > 0) || hl, er = (j < 3) || hr;
        float vl = (j > 0) ? cv[j - 1] : lft;
        float vr = (j < 3) ? cv[j + 1] : rgt;
        float nmn = fminf(fminf(el ? vl : BIGF, er ? vr : BIGF),
                          fminf(hu ? uv[j] : BIGF, hd ? dv[j] : BIGF));
        float nmx = fmaxf(fmaxf(el ? vl : -BIGF, er ? vr : -BIGF),
                          fmaxf(hu ? uv[j] : -BIGF, hd ? dv[j] : -BIGF));
        mnf[j] = (v <= nmn);
        mxf[j] = (v >= nmx);
        if (WANTK) kk[j] = f2key(cv[j]);
    }
}

struct SMP {
    uint32_t keys[LCAP];
    uint32_t h8[8][256];
    uint32_t cnt[2];
    uint32_t pref[2], rank[2], ccnt[2];
    int      flagAll[2];
    float    buf[4][KPTS];
};

__device__ __forceinline__ void binSelN(const uint32_t (*h)[256], int ncop, int lane, uint32_t r,
                                        uint32_t& bsel, uint32_t& newr) {
    uint32_t b0 = 0, b1 = 0, b2 = 0, b3 = 0;
    for (int c = 0; c < ncop; ++c) {
        b0 += h[c][4 * lane];     b1 += h[c][4 * lane + 1];
        b2 += h[c][4 * lane + 2]; b3 += h[c][4 * lane + 3];
    }
    uint32_t s4 = b0 + b1 + b2 + b3, cum = s4;
    #pragma unroll
    for (int d = 1; d < 64; d <<= 1) { uint32_t t = __shfl_up(cum, d); if (lane >= d) cum += t; }
    unsigned long long m = __ballot(cum > r);
    int L = (m == 0ull) ? 63 : __builtin_ctzll(m);
    uint32_t cumL = __shfl(cum, L), s4L = __shfl(s4, L);
    uint32_t a0 = __shfl(b0, L), a1 = __shfl(b1, L), a2 = __shfl(b2, L);
    uint32_t excl = cumL - s4L;
    if (excl + a0 > r)                { bsel = 4u * L;     newr = r - excl; }
    else if (excl + a0 + a1 > r)      { bsel = 4u * L + 1; newr = r - excl - a0; }
    else if (excl + a0 + a1 + a2 > r) { bsel = 4u * L + 2; newr = r - excl - a0 - a1; }
    else                              { bsel = 4u * L + 3; newr = r - excl - a0 - a1 - a2; }
}

__global__ __launch_bounds__(NTH, 8) void topo_pd3_kernel(
        const float* __restrict__ X, const float* __restrict__ Y,
        float* __restrict__ diagOut, int B) {
    __shared__ SMP sm;
    const int tid = threadIdx.x;
    const int lane = tid & 63;
    const int wv = tid >> 6;
    const int bid = blockIdx.x;
    const float* img = ((bid & 1) ? Y : X) + (size_t)(bid >> 1) * NPIX;
    const unsigned long long ltm = (1ull << lane) - 1ull;

    for (int ph = 0; ph < 2; ++ph) {
        for (int i = tid; i < 8 * 256; i += NTH) ((uint32_t*)sm.h8)[i] = 0u;
        if (tid == 0) sm.cnt[0] = 0u;
        __syncthreads();
        for (int it = 0; it < QITERS; ++it) {
            int q = it * NTH + tid;
            int p = q * 4;
            int row = p >> 8;
            bool mnf[4], mxf[4]; uint32_t kk[4];
            stencilRow<true>(img, row, lane, mnf, mxf, kk);
            bool e0 = (ph == 0) ? mnf[0] : mxf[0], e1 = (ph == 0) ? mnf[1] : mxf[1];
            bool e2 = (ph == 0) ? mnf[2] : mxf[2], e3 = (ph == 0) ? mnf[3] : mxf[3];
            unsigned long long m0 = __ballot(e0), m1 = __ballot(e1),
                               m2 = __ballot(e2), m3 = __ballot(e3);
            uint32_t c0 = (uint32_t)__popcll(m0), c1 = (uint32_t)__popcll(m1),
                     c2 = (uint32_t)__popcll(m2), c3 = (uint32_t)__popcll(m3);
            uint32_t base = 0;
            if (lane == 0) base = atomicAdd(&sm.cnt[0], c0 + c1 + c2 + c3);
            base = __shfl(base, 0);
            uint32_t o;
            if (e0) { o = base + (uint32_t)__popcll(m0 & ltm);                sm.keys[o < LCAP ? o : LCAP - 1] = kk[0]; atomicAdd(&sm.h8[wv >> 1][kk[0] >> 24], 1u); }
            if (e1) { o = base + c0 + (uint32_t)__popcll(m1 & ltm);           sm.keys[o < LCAP ? o : LCAP - 1] = kk[1]; atomicAdd(&sm.h8[wv >> 1][kk[1] >> 24], 1u); }
            if (e2) { o = base + c0 + c1 + (uint32_t)__popcll(m2 & ltm);      sm.keys[o < LCAP ? o : LCAP - 1] = kk[2]; atomicAdd(&sm.h8[wv >> 1][kk[2] >> 24], 1u); }
            if (e3) { o = base + c0 + c1 + c2 + (uint32_t)__popcll(m3 & ltm); sm.keys[o < LCAP ? o : LCAP - 1] = kk[3]; atomicAdd(&sm.h8[wv >> 1][kk[3] >> 24], 1u); }
        }
        __syncthreads();
        uint32_t C = sm.cnt[0]; if (C > LCAP) C = LCAP;

        if (wv < 2) {
            bool low = (wv == 0);
            if (C < KPTS) {
                if (lane == 0) { sm.flagAll[wv] = 1; sm.pref[wv] = 0u; sm.rank[wv] = 0u; }
            } else {
                uint32_t bsel, nr;
                binSelN(sm.h8, 8, lane, low ? (KPTS - 1) : (C - KPTS), bsel, nr);
                if (lane == 0) { sm.flagAll[wv] = 0; sm.pref[wv] = bsel; sm.rank[wv] = nr; }
            }
        }
        __syncthreads();

        for (int lvl = 2; lvl >= 0; --lvl) {
            for (int i = tid; i < 2 * 256; i += NTH) ((uint32_t*)sm.h8)[i] = 0u;
            __syncthreads();
            int f0 = sm.flagAll[0], f1 = sm.flagAll[1];
            uint32_t p0 = sm.pref[0], p1 = sm.pref[1];
            const int sp = 8 * (lvl + 1), sb = 8 * lvl;
            for (uint32_t i = tid; i < C; i += NTH) {
                uint32_t k = sm.keys[i], hi = k >> sp, by = (k >> sb) & 255u;
                if (!f0 && hi == p0) atomicAdd(&sm.h8[0][by], 1u);
                if (!f1 && hi == p1) atomicAdd(&sm.h8[1][by], 1u);
            }
            __syncthreads();
            if (wv < 2 && !sm.flagAll[wv]) {
                uint32_t bsel, nr;
                binSelN((const uint32_t(*)[256])&sm.h8[wv], 1, lane, sm.rank[wv], bsel, nr);
                if (lane == 0) { sm.pref[wv] = (sm.pref[wv] << 8) | bsel; sm.rank[wv] = nr; }
            }
            __syncthreads();
        }

        if (tid < 2) sm.ccnt[tid] = 0u;
        __syncthreads();
        const int g0 = (ph == 0) ? 0 : 1;
        const int g1 = (ph == 0) ? 3 : 2;
        {
            int f0 = sm.flagAll[0], f1 = sm.flagAll[1];
            uint32_t t0 = sm.pref[0], t1 = sm.pref[1];
            for (uint32_t i = tid; i < C; i += NTH) {
                uint32_t k = sm.keys[i];
                if (f0 || k < t0) { uint32_t q = atomicAdd(&sm.ccnt[0], 1u); if (q < KPTS) sm.buf[g0][q] = key2f(k); }
                if (f1 || k > t1) { uint32_t q = atomicAdd(&sm.ccnt[1], 1u); if (q < KPTS) sm.buf[g1][q] = key2f(k); }
            }
        }
        __syncthreads();
        if (tid < 2 * KPTS) {
            int l = tid >> 7, i = tid & 127;
            int g = (l == 0) ? g0 : g1;
            if ((uint32_t)i >= sm.ccnt[l])
                sm.buf[g][i] = sm.flagAll[l] ? ((l == 0) ? BIGF : -BIGF) : key2f(sm.pref[l]);
        }
        __syncthreads();
    }

    if (wv < 4) {
        float e[2];
        e[0] = sm.buf[wv][lane];
        e[1] = sm.buf[wv][lane + 64];
        waveSort128(e, wv < 2, lane);
        diagOut[(size_t)bid * 512 + wv * 128 + lane]      = e[0];
        diagOut[(size_t)bid * 512 + wv * 128 + 64 + lane] = e[1];
    }
}

__global__ __launch_bounds__(128) void topo_loss_kernel(
        const float* __restrict__ diag, float* __restrict__ lossOut, int B) {
    const int s = blockIdx.x, i = threadIdx.x;
    const float* xw = diag + (size_t)(2 * s) * 512;
    const float* yw = xw + 512;
    const float H = 0.5f * BIGF;
    float b0x = xw[i], d0x = xw[128 + i], b1x = xw[256 + i], d1x = xw[384 + i];
    float b0y = yw[i], d0y = yw[128 + i], b1y = yw[256 + i], d1y = yw[384 + i];
    bool vx0 = (b0x < H) && (d0x < H);
    float px0b = vx0 ? b0x : 0.f, px0d = vx0 ? fmaxf(d0x, b0x) : 0.f;
    bool vy0 = (b0y < H) && (d0y < H);
    float py0b = vy0 ? b0y : 0.f, py0d = vy0 ? fmaxf(d0y, b0y) : 0.f;
    bool vx1 = (b1x > -H) && (d1x > -H);
    float px1b = vx1 ? b1x : 0.f, px1d = vx1 ? fminf(d1x, b1x) : 0.f;
    bool vy1 = (b1y > -H) && (d1y > -H);
    float py1b = vy1 ? b1y : 0.f, py1d = vy1 ? fminf(d1y, b1y) : 0.f;
    float e0 = px0b - py0b, e1 = px0d - py0d, e2 = px1b - py1b, e3 = px1d - py1d;
    float total = e0 * e0 + e1 * e1 + e2 * e2 + e3 * e3;
    for (int off = 32; off; off >>= 1) total += __shfl_down(total, off);
    __shared__ float lr[2];
    if ((i & 63) == 0) lr[i >> 6] = total;
    __syncthreads();
    if (i == 0) lossOut[s] = lr[0] + lr[1];
}

extern "C" void kernel_launch(void* const* d_in, const int* in_sizes, int n_in,
                              void* d_out, int out_size, void* d_ws, size_t ws_size,
                              hipStream_t stream) {
    const float* X = (const float*)d_in[0];
    const float* Y = (const float*)d_in[1];
    float* out = (float*)d_out;
    const int B = in_sizes[0] / NPIX;   // 256 samples

    size_t lossSz = (size_t)B * sizeof(float);
    size_t cntSz  = (size_t)2 * B * 2 * 16 * sizeof(uint32_t);        // 64 KB
    size_t keysSz = (size_t)2 * B * 2 * LCAP * sizeof(uint32_t);      // 67 MB
    size_t diagSz = (size_t)2 * B * 512 * sizeof(float);              // fallback only

    if (ws_size >= lossSz + cntSz + keysSz) {
        float* lossbuf = (float*)d_ws;
        uint32_t* gcnt16 = (uint32_t*)((char*)d_ws + lossSz);
        uint32_t* gkeys = (uint32_t*)((char*)d_ws + lossSz + cntSz);
        // no memset needed: every segment count is written unconditionally
        topo_scan6_kernel<<<16 * B, 256, 0, stream>>>(X, Y, gkeys, gcnt16, B);
        topo_sel3_kernel<<<B, NTH, 0, stream>>>(gkeys, gcnt16, lossbuf, B);
        topo_reduce_kernel<<<1, 256, 0, stream>>>(lossbuf, out, B);
    } else if (ws_size >= diagSz + lossSz) {
        float* diag = (float*)d_ws;
        float* lossbuf = (float*)((char*)d_ws + diagSz);
        topo_pd3_kernel<<<2 * B, NTH, 0, stream>>>(X, Y, diag, B);
        topo_loss_kernel<<<B, 128, 0, stream>>>(diag, lossbuf, B);
        topo_reduce_kernel<<<1, 256, 0, stream>>>(lossbuf, out, B);
    } else {
        topo_pd3_kernel<<<2 * B, NTH, 0, stream>>>(X, Y, (float*)d_ws, B);
    }
}

// Round 17
// 100.102 us; speedup vs baseline: 1.2460x; 1.2460x over previous
//
#include <hip/hip_runtime.h>
#include <stdint.h>

// TopoLoss: approximate persistence-diagram Wasserstein loss.
// Round 17: best-of combination. K1 = type-split rolling-window scan (r16,
// ~50us). K2 = per-IMAGE sel2 (512 blocks, 2/CU residency — r16's per-sample
// fusion lost residency and cost 50us). K3/K4 = loss + reduce.
// Order statistics bit-exact.

#define KPTS 128
#define BIGF 1.0e9f
#define IMG_W 256
#define NPIX (IMG_W * IMG_W)
#define NTH 1024
#define QITERS (NPIX / 4 / NTH)   // fallback kernel
#define SEGC 1024                 // per-wave segment capacity (E~819, sigma~26: +8sig)
#define LCAP (16 * SEGC)          // 16384 per image-type
#define HPAD 264                  // histogram copy stride (bank-skew: 264%32=8)

__device__ __forceinline__ uint32_t f2key(float f) {
    uint32_t u = __float_as_uint(f);
    return (u & 0x80000000u) ? ~u : (u | 0x80000000u);
}
__device__ __forceinline__ float key2f(uint32_t k) {
    uint32_t u = (k & 0x80000000u) ? (k ^ 0x80000000u) : ~k;
    return __uint_as_float(u);
}

// buf layout: 0=b0 (min,low,asc) 1=d0 (max,low,asc) 2=b1 (max,high,desc) 3=d1 (min,high,desc)

// ---- rolling-window single-type segment scan: 16 rows, one extrema type ----
template <bool ISMAX>
__device__ __forceinline__ uint32_t scanSegT(const float* __restrict__ base0, int r0, int lane,
                                             unsigned long long ltm, uint32_t* __restrict__ dst) {
    uint32_t cnt = 0;
    float4 cur  = *(const float4*)(base0);
    float4 prev = (r0 > 0) ? *(const float4*)(base0 - IMG_W) : cur;   // consumed under hu guard
    float4 next = *(const float4*)(base0 + IMG_W);                    // r0+1 <= 241 < 256 always
    for (int it = 0; it < 16; ++it) {
        const int row = r0 + it;
        const bool hu = row > 0, hd = row < (IMG_W - 1);
        float4 nxt2 = cur;
        if (it < 15 && row + 2 < IMG_W)
            nxt2 = *(const float4*)(base0 + (it + 2) * IMG_W);
        float lft = __shfl_up(cur.w, 1);
        float rgt = __shfl_down(cur.x, 1);
        bool hl = (lane > 0), hr = (lane < 63);
        float cv[4] = {cur.x, cur.y, cur.z, cur.w};
        float uv[4] = {prev.x, prev.y, prev.z, prev.w};
        float dv[4] = {next.x, next.y, next.z, next.w};
        bool fl[4]; uint32_t kk[4];
        #pragma unroll
        for (int j = 0; j < 4; ++j) {
            float v = cv[j];
            bool el = (j > 0) || hl, er = (j < 3) || hr;
            float vl = (j > 0) ? cv[j - 1] : lft;
            float vr = (j < 3) ? cv[j + 1] : rgt;
            if (ISMAX) {
                float nmx = fmaxf(fmaxf(el ? vl : -BIGF, er ? vr : -BIGF),
                                  fmaxf(hu ? uv[j] : -BIGF, hd ? dv[j] : -BIGF));
                fl[j] = (v >= nmx);
            } else {
                float nmn = fminf(fminf(el ? vl : BIGF, er ? vr : BIGF),
                                  fminf(hu ? uv[j] : BIGF, hd ? dv[j] : BIGF));
                fl[j] = (v <= nmn);
            }
            kk[j] = f2key(v);
        }
        unsigned long long m0 = __ballot(fl[0]), m1 = __ballot(fl[1]),
                           m2 = __ballot(fl[2]), m3 = __ballot(fl[3]);
        uint32_t c0 = (uint32_t)__popcll(m0), c1 = (uint32_t)__popcll(m1),
                 c2 = (uint32_t)__popcll(m2), c3 = (uint32_t)__popcll(m3);
        uint32_t o;
        if (fl[0]) { o = cnt + (uint32_t)__popcll(m0 & ltm);                if (o < SEGC) dst[o] = kk[0]; }
        if (fl[1]) { o = cnt + c0 + (uint32_t)__popcll(m1 & ltm);           if (o < SEGC) dst[o] = kk[1]; }
        if (fl[2]) { o = cnt + c0 + c1 + (uint32_t)__popcll(m2 & ltm);      if (o < SEGC) dst[o] = kk[2]; }
        if (fl[3]) { o = cnt + c0 + c1 + c2 + (uint32_t)__popcll(m3 & ltm); if (o < SEGC) dst[o] = kk[3]; }
        cnt += c0 + c1 + c2 + c3;
        prev = cur; cur = next; next = nxt2;
    }
    return cnt;
}

// ---------------- K1: type-split scan (32 waves/image), zero atomics ----------------
__global__ __launch_bounds__(256) void topo_scan6_kernel(
        const float* __restrict__ X, const float* __restrict__ Y,
        uint32_t* __restrict__ gkeys, uint32_t* __restrict__ gcnt16, int B) {
    const int tid = threadIdx.x;
    const int lane = tid & 63;
    const int wv = tid >> 6;
    const int gw = blockIdx.x * 4 + wv;      // 0..2B*32-1
    const int im = gw >> 5;                  // image id (32 waves/image)
    const int type = (gw >> 4) & 1;          // 0=min, 1=max
    const int seg = gw & 15;
    const int r0 = seg * 16;
    const float* img = ((im & 1) ? Y : X) + (size_t)(im >> 1) * NPIX;
    const float* base0 = img + (size_t)r0 * IMG_W + lane * 4;
    const unsigned long long ltm = (1ull << lane) - 1ull;

    uint32_t* dst = gkeys + (size_t)(im * 2 + type) * LCAP + seg * SEGC;
    uint32_t cnt = type ? scanSegT<true>(base0, r0, lane, ltm, dst)
                        : scanSegT<false>(base0, r0, lane, ltm, dst);
    if (lane == 0)
        gcnt16[(im * 2 + type) * 16 + seg] = (cnt < SEGC) ? cnt : SEGC;
}

// ---------------- K2: per-image segment-compacting radix select + register sort ----------------
struct SMQ {
    uint32_t keys[LCAP];      // 64 KB
    uint32_t h8[8 * HPAD];    // 8.25 KB (skewed copies)
    uint32_t pref[2], rank[2], ccnt[2];
    int      flagAll[2];
    float    buf[4][KPTS];    // 2 KB
};                            // ~74.5 KB -> 2 blocks/CU

__device__ __forceinline__ void binSelP(const uint32_t* h, int ncop, int lane, uint32_t r,
                                        uint32_t& bsel, uint32_t& newr) {
    uint32_t b0 = 0, b1 = 0, b2 = 0, b3 = 0;
    for (int c = 0; c < ncop; ++c) {
        const uint32_t* hh = h + c * HPAD;
        b0 += hh[4 * lane];     b1 += hh[4 * lane + 1];
        b2 += hh[4 * lane + 2]; b3 += hh[4 * lane + 3];
    }
    uint32_t s4 = b0 + b1 + b2 + b3, cum = s4;
    #pragma unroll
    for (int d = 1; d < 64; d <<= 1) { uint32_t t = __shfl_up(cum, d); if (lane >= d) cum += t; }
    unsigned long long m = __ballot(cum > r);
    int L = (m == 0ull) ? 63 : __builtin_ctzll(m);
    uint32_t cumL = __shfl(cum, L), s4L = __shfl(s4, L);
    uint32_t a0 = __shfl(b0, L), a1 = __shfl(b1, L), a2 = __shfl(b2, L);
    uint32_t excl = cumL - s4L;
    if (excl + a0 > r)                { bsel = 4u * L;     newr = r - excl; }
    else if (excl + a0 + a1 > r)      { bsel = 4u * L + 1; newr = r - excl - a0; }
    else if (excl + a0 + a1 + a2 > r) { bsel = 4u * L + 2; newr = r - excl - a0 - a1; }
    else                              { bsel = 4u * L + 3; newr = r - excl - a0 - a1 - a2; }
}

// 128-element bitonic sort in registers, one wave, 2 elems/lane.
__device__ __forceinline__ void waveSort128(float e[2], bool asc, int lane) {
    for (int size = 2; size <= 128; size <<= 1) {
        for (int stride = size >> 1; stride > 0; stride >>= 1) {
            if (stride == 64) {
                float a = e[0], b = e[1];
                e[0] = asc ? fminf(a, b) : fmaxf(a, b);
                e[1] = asc ? fmaxf(a, b) : fminf(a, b);
            } else {
                #pragma unroll
                for (int r = 0; r < 2; ++r) {
                    int i = r * 64 + lane;
                    float v = e[r];
                    float w = __shfl_xor(v, stride);
                    bool up = ((i & size) == 0) ? asc : !asc;
                    bool lower = (i & stride) == 0;
                    float mn = fminf(v, w), mx = fmaxf(v, w);
                    e[r] = (lower == up) ? mn : mx;
                }
            }
        }
    }
}

__global__ __launch_bounds__(NTH, 8) void topo_sel2_kernel(
        const uint32_t* __restrict__ gkeys, const uint32_t* __restrict__ gcnt16,
        float* __restrict__ diagOut, int B) {
    __shared__ SMQ sm;
    const int tid = threadIdx.x;
    const int lane = tid & 63;
    const int wv = tid >> 6;        // 16 waves
    const int im = blockIdx.x;
    const int hc = lane & 7;

    for (int ph = 0; ph < 2; ++ph) {   // 0: minima -> {b0,d1}; 1: maxima -> {d0,b1}
        for (int i = tid; i < 8 * HPAD; i += NTH) sm.h8[i] = 0u;
        __syncthreads();
        const uint32_t* list = gkeys + (size_t)(im * 2 + ph) * LCAP;
        const uint32_t* cnts = gcnt16 + (im * 2 + ph) * 16;

        // every wave: read 16 segment counts, shfl prefix scan -> my offset / total
        uint32_t cw = (lane < 16) ? cnts[lane] : 0;
        uint32_t inc = cw;
        #pragma unroll
        for (int d = 1; d < 16; d <<= 1) { uint32_t t = __shfl_up(inc, d); if (lane >= d) inc += t; }
        uint32_t C = __shfl(inc, 15);                 // total count
        uint32_t myCnt = __shfl(cw, wv);              // my segment's count
        uint32_t myOff = __shfl(inc, wv) - myCnt;     // exclusive prefix

        // wave wv compacts segment wv into LDS (+ lane-privatized skewed MSB hist)
        for (uint32_t i = lane; i < myCnt; i += 64) {
            uint32_t k = list[wv * SEGC + i];
            sm.keys[myOff + i] = k;
            atomicAdd(&sm.h8[hc * HPAD + (k >> 24)], 1u);
        }
        __syncthreads();

        // top-level select: wave0 = low sel, wave1 = high sel
        if (wv < 2) {
            bool low = (wv == 0);
            if (C < KPTS) {
                if (lane == 0) { sm.flagAll[wv] = 1; sm.pref[wv] = 0u; sm.rank[wv] = 0u; }
            } else {
                uint32_t bsel, nr;
                binSelP(sm.h8, 8, lane, low ? (KPTS - 1) : (C - KPTS), bsel, nr);
                if (lane == 0) { sm.flagAll[wv] = 0; sm.pref[wv] = bsel; sm.rank[wv] = nr; }
            }
        }
        __syncthreads();

        // levels 2..0: prefix-filtered LDS list scans
        for (int lvl = 2; lvl >= 0; --lvl) {
            for (int i = tid; i < 2 * HPAD; i += NTH) sm.h8[i] = 0u;
            __syncthreads();
            int f0 = sm.flagAll[0], f1 = sm.flagAll[1];
            uint32_t p0 = sm.pref[0], p1 = sm.pref[1];
            const int sp = 8 * (lvl + 1), sb = 8 * lvl;
            for (uint32_t i = tid; i < C; i += NTH) {
                uint32_t k = sm.keys[i], hi = k >> sp, by = (k >> sb) & 255u;
                if (!f0 && hi == p0) atomicAdd(&sm.h8[by], 1u);
                if (!f1 && hi == p1) atomicAdd(&sm.h8[HPAD + by], 1u);
            }
            __syncthreads();
            if (wv < 2 && !sm.flagAll[wv]) {
                uint32_t bsel, nr;
                binSelP(&sm.h8[wv * HPAD], 1, lane, sm.rank[wv], bsel, nr);
                if (lane == 0) { sm.pref[wv] = (sm.pref[wv] << 8) | bsel; sm.rank[wv] = nr; }
            }
            __syncthreads();
        }

        // collect strict winners, tie/sentinel pad
        if (tid < 2) sm.ccnt[tid] = 0u;
        __syncthreads();
        const int g0 = (ph == 0) ? 0 : 1;
        const int g1 = (ph == 0) ? 3 : 2;
        {
            int f0 = sm.flagAll[0], f1 = sm.flagAll[1];
            uint32_t t0 = sm.pref[0], t1 = sm.pref[1];
            for (uint32_t i = tid; i < C; i += NTH) {
                uint32_t k = sm.keys[i];
                if (f0 || k < t0) { uint32_t s = atomicAdd(&sm.ccnt[0], 1u); if (s < KPTS) sm.buf[g0][s] = key2f(k); }
                if (f1 || k > t1) { uint32_t s = atomicAdd(&sm.ccnt[1], 1u); if (s < KPTS) sm.buf[g1][s] = key2f(k); }
            }
        }
        __syncthreads();
        if (tid < 2 * KPTS) {
            int l = tid >> 7, i = tid & 127;
            int g = (l == 0) ? g0 : g1;
            if ((uint32_t)i >= sm.ccnt[l])
                sm.buf[g][i] = sm.flagAll[l] ? ((l == 0) ? BIGF : -BIGF) : key2f(sm.pref[l]);
        }
        __syncthreads();
    }

    // 4 register-resident 128-elem bitonic sorts (waves 0..3, no barriers)
    if (wv < 4) {
        float e[2];
        e[0] = sm.buf[wv][lane];
        e[1] = sm.buf[wv][lane + 64];
        waveSort128(e, wv < 2, lane);
        diagOut[(size_t)im * 512 + wv * 128 + lane]      = e[0];
        diagOut[(size_t)im * 512 + wv * 128 + 64 + lane] = e[1];
    }
}

// ---------------- loss + reduce ----------------
__global__ __launch_bounds__(128) void topo_loss_kernel(
        const float* __restrict__ diag, float* __restrict__ lossOut, int B) {
    const int s = blockIdx.x, i = threadIdx.x;
    const float* xw = diag + (size_t)(2 * s) * 512;
    const float* yw = xw + 512;
    const float H = 0.5f * BIGF;
    float b0x = xw[i], d0x = xw[128 + i], b1x = xw[256 + i], d1x = xw[384 + i];
    float b0y = yw[i], d0y = yw[128 + i], b1y = yw[256 + i], d1y = yw[384 + i];
    bool vx0 = (b0x < H) && (d0x < H);
    float px0b = vx0 ? b0x : 0.f, px0d = vx0 ? fmaxf(d0x, b0x) : 0.f;
    bool vy0 = (b0y < H) && (d0y < H);
    float py0b = vy0 ? b0y : 0.f, py0d = vy0 ? fmaxf(d0y, b0y) : 0.f;
    bool vx1 = (b1x > -H) && (d1x > -H);
    float px1b = vx1 ? b1x : 0.f, px1d = vx1 ? fminf(d1x, b1x) : 0.f;
    bool vy1 = (b1y > -H) && (d1y > -H);
    float py1b = vy1 ? b1y : 0.f, py1d = vy1 ? fminf(d1y, b1y) : 0.f;
    float e0 = px0b - py0b, e1 = px0d - py0d, e2 = px1b - py1b, e3 = px1d - py1d;
    float total = e0 * e0 + e1 * e1 + e2 * e2 + e3 * e3;
    for (int off = 32; off; off >>= 1) total += __shfl_down(total, off);
    __shared__ float lr[2];
    if ((i & 63) == 0) lr[i >> 6] = total;
    __syncthreads();
    if (i == 0) lossOut[s] = lr[0] + lr[1];
}

__global__ void topo_reduce_kernel(const float* __restrict__ ws, float* __restrict__ out, int B) {
    float v = 0.f;
    for (int i = threadIdx.x; i < B; i += 256) v += ws[i];
    __shared__ float r[4];
    for (int off = 32; off; off >>= 1) v += __shfl_down(v, off);
    if ((threadIdx.x & 63) == 0) r[threadIdx.x >> 6] = v;
    __syncthreads();
    if (threadIdx.x == 0) out[0] = (r[0] + r[1] + r[2] + r[3]) / (float)B;
}

// ================= fallback: fused pd3 kernel (round-8/9 proven) =================
template <bool WANTK>
__device__ __forceinline__ void stencilRow(const float* __restrict__ img, int row, int lane,
                                           bool mnf[4], bool mxf[4], uint32_t kk[4]) {
    const float* base = img + (size_t)row * IMG_W;
    float4 cur = *(const float4*)(base + lane * 4);
    bool hu = row > 0, hd = row < (IMG_W - 1);
    float4 up = cur, dn = cur;
    if (hu) up = *(const float4*)(base - IMG_W + lane * 4);
    if (hd) dn = *(const float4*)(base + IMG_W + lane * 4);
    float lft = __shfl_up(cur.w, 1);
    float rgt = __shfl_down(cur.x, 1);
    bool hl = (lane > 0), hr = (lane < 63);
    float cv[4] = {cur.x, cur.y, cur.z, cur.w};
    float uv[4] = {up.x, up.y, up.z, up.w};
    float dv[4] = {dn.x, dn.y, dn.z, dn.w};
    #pragma unroll
    for (int j = 0; j < 4; ++j) {
        float v = cv[j];
        bool el = (j > 0) || hl, er = (j < 3) || hr;
        float vl = (j > 0) ? cv[j - 1] : lft;
        float vr = (j < 3) ? cv[j + 1] : rgt;
        float nmn = fminf(fminf(el ? vl : BIGF, er ? vr : BIGF),
                          fminf(hu ? uv[j] : BIGF, hd ? dv[j] : BIGF));
        float nmx = fmaxf(fmaxf(el ? vl : -BIGF, er ? vr : -BIGF),
                          fmaxf(hu ? uv[j] : -BIGF, hd ? dv[j] : -BIGF));
        mnf[j] = (v <= nmn);
        mxf[j] = (v >= nmx);
        if (WANTK) kk[j] = f2key(cv[j]);
    }
}

struct SMP {
    uint32_t keys[LCAP];
    uint32_t h8[8][256];
    uint32_t cnt[2];
    uint32_t pref[2], rank[2], ccnt[2];
    int      flagAll[2];
    float    buf[4][KPTS];
};

__device__ __forceinline__ void binSelN(const uint32_t (*h)[256], int ncop, int lane, uint32_t r,
                                        uint32_t& bsel, uint32_t& newr) {
    uint32_t b0 = 0, b1 = 0, b2 = 0, b3 = 0;
    for (int c = 0; c < ncop; ++c) {
        b0 += h[c][4 * lane];     b1 += h[c][4 * lane + 1];
        b2 += h[c][4 * lane + 2]; b3 += h[c][4 * lane + 3];
    }
    uint32_t s4 = b0 + b1 + b2 + b3, cum = s4;
    #pragma unroll
    for (int d = 1; d < 64; d <<= 1) { uint32_t t = __shfl_up(cum, d); if (lane >= d) cum += t; }
    unsigned long long m = __ballot(cum > r);
    int L = (m == 0ull) ? 63 : __builtin_ctzll(m);
    uint32_t cumL = __shfl(cum, L), s4L = __shfl(s4, L);
    uint32_t a0 = __shfl(b0, L), a1 = __shfl(b1, L), a2 = __shfl(b2, L);
    uint32_t excl = cumL - s4L;
    if (excl + a0 > r)                { bsel = 4u * L;     newr = r - excl; }
    else if (excl + a0 + a1 > r)      { bsel = 4u * L + 1; newr = r - excl - a0; }
    else if (excl + a0 + a1 + a2 > r) { bsel = 4u * L + 2; newr = r - excl - a0 - a1; }
    else                              { bsel = 4u * L + 3; newr = r - excl - a0 - a1 - a2; }
}

__global__ __launch_bounds__(NTH, 8) void topo_pd3_kernel(
        const float* __restrict__ X, const float* __restrict__ Y,
        float* __restrict__ diagOut, int B) {
    __shared__ SMP sm;
    const int tid = threadIdx.x;
    const int lane = tid & 63;
    const int wv = tid >> 6;
    const int bid = blockIdx.x;
    const float* img = ((bid & 1) ? Y : X) + (size_t)(bid >> 1) * NPIX;
    const unsigned long long ltm = (1ull << lane) - 1ull;

    for (int ph = 0; ph < 2; ++ph) {
        for (int i = tid; i < 8 * 256; i += NTH) ((uint32_t*)sm.h8)[i] = 0u;
        if (tid == 0) sm.cnt[0] = 0u;
        __syncthreads();
        for (int it = 0; it < QITERS; ++it) {
            int q = it * NTH + tid;
            int p = q * 4;
            int row = p >> 8;
            bool mnf[4], mxf[4]; uint32_t kk[4];
            stencilRow<true>(img, row, lane, mnf, mxf, kk);
            bool e0 = (ph == 0) ? mnf[0] : mxf[0], e1 = (ph == 0) ? mnf[1] : mxf[1];
            bool e2 = (ph == 0) ? mnf[2] : mxf[2], e3 = (ph == 0) ? mnf[3] : mxf[3];
            unsigned long long m0 = __ballot(e0), m1 = __ballot(e1),
                               m2 = __ballot(e2), m3 = __ballot(e3);
            uint32_t c0 = (uint32_t)__popcll(m0), c1 = (uint32_t)__popcll(m1),
                     c2 = (uint32_t)__popcll(m2), c3 = (uint32_t)__popcll(m3);
            uint32_t base = 0;
            if (lane == 0) base = atomicAdd(&sm.cnt[0], c0 + c1 + c2 + c3);
            base = __shfl(base, 0);
            uint32_t o;
            if (e0) { o = base + (uint32_t)__popcll(m0 & ltm);                sm.keys[o < LCAP ? o : LCAP - 1] = kk[0]; atomicAdd(&sm.h8[wv >> 1][kk[0] >> 24], 1u); }
            if (e1) { o = base + c0 + (uint32_t)__popcll(m1 & ltm);           sm.keys[o < LCAP ? o : LCAP - 1] = kk[1]; atomicAdd(&sm.h8[wv >> 1][kk[1] >> 24], 1u); }
            if (e2) { o = base + c0 + c1 + (uint32_t)__popcll(m2 & ltm);      sm.keys[o < LCAP ? o : LCAP - 1] = kk[2]; atomicAdd(&sm.h8[wv >> 1][kk[2] >> 24], 1u); }
            if (e3) { o = base + c0 + c1 + c2 + (uint32_t)__popcll(m3 & ltm); sm.keys[o < LCAP ? o : LCAP - 1] = kk[3]; atomicAdd(&sm.h8[wv >> 1][kk[3] >> 24], 1u); }
        }
        __syncthreads();
        uint32_t C = sm.cnt[0]; if (C > LCAP) C = LCAP;

        if (wv < 2) {
            bool low = (wv == 0);
            if (C < KPTS) {
                if (lane == 0) { sm.flagAll[wv] = 1; sm.pref[wv] = 0u; sm.rank[wv] = 0u; }
            } else {
                uint32_t bsel, nr;
                binSelN(sm.h8, 8, lane, low ? (KPTS - 1) : (C - KPTS), bsel, nr);
                if (lane == 0) { sm.flagAll[wv] = 0; sm.pref[wv] = bsel; sm.rank[wv] = nr; }
            }
        }
        __syncthreads();

        for (int lvl = 2; lvl >= 0; --lvl) {
            for (int i = tid; i < 2 * 256; i += NTH) ((uint32_t*)sm.h8)[i] = 0u;
            __syncthreads();
            int f0 = sm.flagAll[0], f1 = sm.flagAll[1];
            uint32_t p0 = sm.pref[0], p1 = sm.pref[1];
            const int sp = 8 * (lvl + 1), sb = 8 * lvl;
            for (uint32_t i = tid; i < C; i += NTH) {
                uint32_t k = sm.keys[i], hi = k >> sp, by = (k >> sb) & 255u;
                if (!f0 && hi == p0) atomicAdd(&sm.h8[0][by], 1u);
                if (!f1 && hi == p1) atomicAdd(&sm.h8[1][by], 1u);
            }
            __syncthreads();
            if (wv < 2 && !sm.flagAll[wv]) {
                uint32_t bsel, nr;
                binSelN((const uint32_t(*)[256])&sm.h8[wv], 1, lane, sm.rank[wv], bsel, nr);
                if (lane == 0) { sm.pref[wv] = (sm.pref[wv] << 8) | bsel; sm.rank[wv] = nr; }
            }
            __syncthreads();
        }

        if (tid < 2) sm.ccnt[tid] = 0u;
        __syncthreads();
        const int g0 = (ph == 0) ? 0 : 1;
        const int g1 = (ph == 0) ? 3 : 2;
        {
            int f0 = sm.flagAll[0], f1 = sm.flagAll[1];
            uint32_t t0 = sm.pref[0], t1 = sm.pref[1];
            for (uint32_t i = tid; i < C; i += NTH) {
                uint32_t k = sm.keys[i];
                if (f0 || k < t0) { uint32_t q = atomicAdd(&sm.ccnt[0], 1u); if (q < KPTS) sm.buf[g0][q] = key2f(k); }
                if (f1 || k > t1) { uint32_t q = atomicAdd(&sm.ccnt[1], 1u); if (q < KPTS) sm.buf[g1][q] = key2f(k); }
            }
        }
        __syncthreads();
        if (tid < 2 * KPTS) {
            int l = tid >> 7, i = tid & 127;
            int g = (l == 0) ? g0 : g1;
            if ((uint32_t)i >= sm.ccnt[l])
                sm.buf[g][i] = sm.flagAll[l] ? ((l == 0) ? BIGF : -BIGF) : key2f(sm.pref[l]);
        }
        __syncthreads();
    }

    if (wv < 4) {
        float e[2];
        e[0] = sm.buf[wv][lane];
        e[1] = sm.buf[wv][lane + 64];
        waveSort128(e, wv < 2, lane);
        diagOut[(size_t)bid * 512 + wv * 128 + lane]      = e[0];
        diagOut[(size_t)bid * 512 + wv * 128 + 64 + lane] = e[1];
    }
}

extern "C" void kernel_launch(void* const* d_in, const int* in_sizes, int n_in,
                              void* d_out, int out_size, void* d_ws, size_t ws_size,
                              hipStream_t stream) {
    const float* X = (const float*)d_in[0];
    const float* Y = (const float*)d_in[1];
    float* out = (float*)d_out;
    const int B = in_sizes[0] / NPIX;   // 256 samples

    size_t diagSz = (size_t)2 * B * 512 * sizeof(float);              // 2 MB
    size_t lossSz = (size_t)B * sizeof(float);
    size_t cntSz  = (size_t)2 * B * 2 * 16 * sizeof(uint32_t);        // 64 KB
    size_t keysSz = (size_t)2 * B * 2 * LCAP * sizeof(uint32_t);      // 67 MB

    if (ws_size >= diagSz + lossSz + cntSz + keysSz) {
        float* diag = (float*)d_ws;
        float* lossbuf = (float*)((char*)d_ws + diagSz);
        uint32_t* gcnt16 = (uint32_t*)((char*)d_ws + diagSz + lossSz);
        uint32_t* gkeys = (uint32_t*)((char*)d_ws + diagSz + lossSz + cntSz);
        // no memset needed: every segment count is written unconditionally
        topo_scan6_kernel<<<16 * B, 256, 0, stream>>>(X, Y, gkeys, gcnt16, B);
        topo_sel2_kernel<<<2 * B, NTH, 0, stream>>>(gkeys, gcnt16, diag, B);
        topo_loss_kernel<<<B, 128, 0, stream>>>(diag, lossbuf, B);
        topo_reduce_kernel<<<1, 256, 0, stream>>>(lossbuf, out, B);
    } else if (ws_size >= diagSz + lossSz) {
        float* diag = (float*)d_ws;
        float* lossbuf = (float*)((char*)d_ws + diagSz);
        topo_pd3_kernel<<<2 * B, NTH, 0, stream>>>(X, Y, diag, B);
        topo_loss_kernel<<<B, 128, 0, stream>>>(diag, lossbuf, B);
        topo_reduce_kernel<<<1, 256, 0, stream>>>(lossbuf, out, B);
    } else {
        topo_pd3_kernel<<<2 * B, NTH, 0, stream>>>(X, Y, (float*)d_ws, B);
    }
}

// Round 18
// 95.301 us; speedup vs baseline: 1.3088x; 1.0504x over previous
//
#include <hip/hip_runtime.h>
#include <stdint.h>

// TopoLoss: approximate persistence-diagram Wasserstein loss.
// Round 18: revert to COMBINED-type scan (r15's scan4: one image read; r16/17's
// type-split doubled FETCH and regressed) and deepen its software pipeline:
// 5-register rolling window, prefetch issued 3 rows ahead, consumed 3 iters
// later (2 loads in flight vs 1). sel2/loss/reduce unchanged (proven).
// Order statistics bit-exact.

#define KPTS 128
#define BIGF 1.0e9f
#define IMG_W 256
#define NPIX (IMG_W * IMG_W)
#define NTH 1024
#define QITERS (NPIX / 4 / NTH)   // fallback kernel
#define SEGC 1024                 // per-wave segment capacity (E~819, sigma~26: +8sig)
#define LCAP (16 * SEGC)          // 16384 per image-type
#define HPAD 264                  // histogram copy stride (bank-skew: 264%32=8)

__device__ __forceinline__ uint32_t f2key(float f) {
    uint32_t u = __float_as_uint(f);
    return (u & 0x80000000u) ? ~u : (u | 0x80000000u);
}
__device__ __forceinline__ float key2f(uint32_t k) {
    uint32_t u = (k & 0x80000000u) ? (k ^ 0x80000000u) : ~k;
    return __uint_as_float(u);
}

// buf layout: 0=b0 (min,low,asc) 1=d0 (max,low,asc) 2=b1 (max,high,desc) 3=d1 (min,high,desc)

// ---------------- K1: combined-type scan, depth-2 pipelined window ----------------
__global__ __launch_bounds__(256) void topo_scan7_kernel(
        const float* __restrict__ X, const float* __restrict__ Y,
        uint32_t* __restrict__ gkeys, uint32_t* __restrict__ gcnt16, int B) {
    const int tid = threadIdx.x;
    const int lane = tid & 63;
    const int wv = tid >> 6;
    const int gw = blockIdx.x * 4 + wv;      // 0..2B*16-1
    const int im = gw >> 4;                  // image id (16 waves/image)
    const int seg = gw & 15;
    const int r0 = seg * 16;
    const float* img = ((im & 1) ? Y : X) + (size_t)(im >> 1) * NPIX;
    const float* base0 = img + (size_t)r0 * IMG_W + lane * 4;
    const unsigned long long ltm = (1ull << lane) - 1ull;

    uint32_t* dMin = gkeys + (size_t)(im * 2 + 0) * LCAP + seg * SEGC;
    uint32_t* dMax = gkeys + (size_t)(im * 2 + 1) * LCAP + seg * SEGC;
    uint32_t cMin = 0, cMax = 0;

    // rolling window rows r-1..r+2, one prefetch (r+3) in flight on top
    float4 cur  = *(const float4*)(base0);                             // row r0
    float4 prev = (r0 > 0) ? *(const float4*)(base0 - IMG_W) : cur;    // consumed under hu
    float4 nx1  = *(const float4*)(base0 + IMG_W);                     // r0+1 <= 241, valid
    float4 nx2  = *(const float4*)(base0 + 2 * IMG_W);                 // r0+2 <= 242, valid

    for (int it = 0; it < 16; ++it) {
        const int row = r0 + it;
        const bool hu = row > 0, hd = row < (IMG_W - 1);
        // prefetch row r+3 (becomes nx1 for compute at it+2)
        float4 nx3 = cur;                                              // dummy, guarded use
        if (it <= 13 && row + 3 < IMG_W)
            nx3 = *(const float4*)(base0 + (it + 3) * IMG_W);

        float lft = __shfl_up(cur.w, 1);
        float rgt = __shfl_down(cur.x, 1);
        bool hl = (lane > 0), hr = (lane < 63);
        float cv[4] = {cur.x, cur.y, cur.z, cur.w};
        float uv[4] = {prev.x, prev.y, prev.z, prev.w};
        float dv[4] = {nx1.x, nx1.y, nx1.z, nx1.w};
        bool mnf[4], mxf[4];
        uint32_t kk[4];
        #pragma unroll
        for (int j = 0; j < 4; ++j) {
            float v = cv[j];
            bool el = (j > 0) || hl, er = (j < 3) || hr;
            float vl = (j > 0) ? cv[j - 1] : lft;
            float vr = (j < 3) ? cv[j + 1] : rgt;
            float nmn = fminf(fminf(el ? vl : BIGF, er ? vr : BIGF),
                              fminf(hu ? uv[j] : BIGF, hd ? dv[j] : BIGF));
            float nmx = fmaxf(fmaxf(el ? vl : -BIGF, er ? vr : -BIGF),
                              fmaxf(hu ? uv[j] : -BIGF, hd ? dv[j] : -BIGF));
            mnf[j] = (v <= nmn);
            mxf[j] = (v >= nmx);
            kk[j] = f2key(v);
        }
        {
            unsigned long long m0 = __ballot(mnf[0]), m1 = __ballot(mnf[1]),
                               m2 = __ballot(mnf[2]), m3 = __ballot(mnf[3]);
            uint32_t c0 = (uint32_t)__popcll(m0), c1 = (uint32_t)__popcll(m1),
                     c2 = (uint32_t)__popcll(m2), c3 = (uint32_t)__popcll(m3);
            uint32_t o;
            if (mnf[0]) { o = cMin + (uint32_t)__popcll(m0 & ltm);                if (o < SEGC) dMin[o] = kk[0]; }
            if (mnf[1]) { o = cMin + c0 + (uint32_t)__popcll(m1 & ltm);           if (o < SEGC) dMin[o] = kk[1]; }
            if (mnf[2]) { o = cMin + c0 + c1 + (uint32_t)__popcll(m2 & ltm);      if (o < SEGC) dMin[o] = kk[2]; }
            if (mnf[3]) { o = cMin + c0 + c1 + c2 + (uint32_t)__popcll(m3 & ltm); if (o < SEGC) dMin[o] = kk[3]; }
            cMin += c0 + c1 + c2 + c3;
        }
        {
            unsigned long long m0 = __ballot(mxf[0]), m1 = __ballot(mxf[1]),
                               m2 = __ballot(mxf[2]), m3 = __ballot(mxf[3]);
            uint32_t c0 = (uint32_t)__popcll(m0), c1 = (uint32_t)__popcll(m1),
                     c2 = (uint32_t)__popcll(m2), c3 = (uint32_t)__popcll(m3);
            uint32_t o;
            if (mxf[0]) { o = cMax + (uint32_t)__popcll(m0 & ltm);                if (o < SEGC) dMax[o] = kk[0]; }
            if (mxf[1]) { o = cMax + c0 + (uint32_t)__popcll(m1 & ltm);           if (o < SEGC) dMax[o] = kk[1]; }
            if (mxf[2]) { o = cMax + c0 + c1 + (uint32_t)__popcll(m2 & ltm);      if (o < SEGC) dMax[o] = kk[2]; }
            if (mxf[3]) { o = cMax + c0 + c1 + c2 + (uint32_t)__popcll(m3 & ltm); if (o < SEGC) dMax[o] = kk[3]; }
            cMax += c0 + c1 + c2 + c3;
        }
        prev = cur; cur = nx1; nx1 = nx2; nx2 = nx3;   // slide
    }
    if (lane == 0) {
        gcnt16[(im * 2 + 0) * 16 + seg] = (cMin < SEGC) ? cMin : SEGC;
        gcnt16[(im * 2 + 1) * 16 + seg] = (cMax < SEGC) ? cMax : SEGC;
    }
}

// ---------------- K2: per-image segment-compacting radix select + register sort ----------------
struct SMQ {
    uint32_t keys[LCAP];      // 64 KB
    uint32_t h8[8 * HPAD];    // 8.25 KB (skewed copies)
    uint32_t pref[2], rank[2], ccnt[2];
    int      flagAll[2];
    float    buf[4][KPTS];    // 2 KB
};                            // ~74.5 KB -> 2 blocks/CU

__device__ __forceinline__ void binSelP(const uint32_t* h, int ncop, int lane, uint32_t r,
                                        uint32_t& bsel, uint32_t& newr) {
    uint32_t b0 = 0, b1 = 0, b2 = 0, b3 = 0;
    for (int c = 0; c < ncop; ++c) {
        const uint32_t* hh = h + c * HPAD;
        b0 += hh[4 * lane];     b1 += hh[4 * lane + 1];
        b2 += hh[4 * lane + 2]; b3 += hh[4 * lane + 3];
    }
    uint32_t s4 = b0 + b1 + b2 + b3, cum = s4;
    #pragma unroll
    for (int d = 1; d < 64; d <<= 1) { uint32_t t = __shfl_up(cum, d); if (lane >= d) cum += t; }
    unsigned long long m = __ballot(cum > r);
    int L = (m == 0ull) ? 63 : __builtin_ctzll(m);
    uint32_t cumL = __shfl(cum, L), s4L = __shfl(s4, L);
    uint32_t a0 = __shfl(b0, L), a1 = __shfl(b1, L), a2 = __shfl(b2, L);
    uint32_t excl = cumL - s4L;
    if (excl + a0 > r)                { bsel = 4u * L;     newr = r - excl; }
    else if (excl + a0 + a1 > r)      { bsel = 4u * L + 1; newr = r - excl - a0; }
    else if (excl + a0 + a1 + a2 > r) { bsel = 4u * L + 2; newr = r - excl - a0 - a1; }
    else                              { bsel = 4u * L + 3; newr = r - excl - a0 - a1 - a2; }
}

// 128-element bitonic sort in registers, one wave, 2 elems/lane.
__device__ __forceinline__ void waveSort128(float e[2], bool asc, int lane) {
    for (int size = 2; size <= 128; size <<= 1) {
        for (int stride = size >> 1; stride > 0; stride >>= 1) {
            if (stride == 64) {
                float a = e[0], b = e[1];
                e[0] = asc ? fminf(a, b) : fmaxf(a, b);
                e[1] = asc ? fmaxf(a, b) : fminf(a, b);
            } else {
                #pragma unroll
                for (int r = 0; r < 2; ++r) {
                    int i = r * 64 + lane;
                    float v = e[r];
                    float w = __shfl_xor(v, stride);
                    bool up = ((i & size) == 0) ? asc : !asc;
                    bool lower = (i & stride) == 0;
                    float mn = fminf(v, w), mx = fmaxf(v, w);
                    e[r] = (lower == up) ? mn : mx;
                }
            }
        }
    }
}

__global__ __launch_bounds__(NTH, 8) void topo_sel2_kernel(
        const uint32_t* __restrict__ gkeys, const uint32_t* __restrict__ gcnt16,
        float* __restrict__ diagOut, int B) {
    __shared__ SMQ sm;
    const int tid = threadIdx.x;
    const int lane = tid & 63;
    const int wv = tid >> 6;        // 16 waves
    const int im = blockIdx.x;
    const int hc = lane & 7;

    for (int ph = 0; ph < 2; ++ph) {   // 0: minima -> {b0,d1}; 1: maxima -> {d0,b1}
        for (int i = tid; i < 8 * HPAD; i += NTH) sm.h8[i] = 0u;
        __syncthreads();
        const uint32_t* list = gkeys + (size_t)(im * 2 + ph) * LCAP;
        const uint32_t* cnts = gcnt16 + (im * 2 + ph) * 16;

        // every wave: read 16 segment counts, shfl prefix scan -> my offset / total
        uint32_t cw = (lane < 16) ? cnts[lane] : 0;
        uint32_t inc = cw;
        #pragma unroll
        for (int d = 1; d < 16; d <<= 1) { uint32_t t = __shfl_up(inc, d); if (lane >= d) inc += t; }
        uint32_t C = __shfl(inc, 15);                 // total count
        uint32_t myCnt = __shfl(cw, wv);              // my segment's count
        uint32_t myOff = __shfl(inc, wv) - myCnt;     // exclusive prefix

        // wave wv compacts segment wv into LDS (+ lane-privatized skewed MSB hist)
        for (uint32_t i = lane; i < myCnt; i += 64) {
            uint32_t k = list[wv * SEGC + i];
            sm.keys[myOff + i] = k;
            atomicAdd(&sm.h8[hc * HPAD + (k >> 24)], 1u);
        }
        __syncthreads();

        // top-level select: wave0 = low sel, wave1 = high sel
        if (wv < 2) {
            bool low = (wv == 0);
            if (C < KPTS) {
                if (lane == 0) { sm.flagAll[wv] = 1; sm.pref[wv] = 0u; sm.rank[wv] = 0u; }
            } else {
                uint32_t bsel, nr;
                binSelP(sm.h8, 8, lane, low ? (KPTS - 1) : (C - KPTS), bsel, nr);
                if (lane == 0) { sm.flagAll[wv] = 0; sm.pref[wv] = bsel; sm.rank[wv] = nr; }
            }
        }
        __syncthreads();

        // levels 2..0: prefix-filtered LDS list scans
        for (int lvl = 2; lvl >= 0; --lvl) {
            for (int i = tid; i < 2 * HPAD; i += NTH) sm.h8[i] = 0u;
            __syncthreads();
            int f0 = sm.flagAll[0], f1 = sm.flagAll[1];
            uint32_t p0 = sm.pref[0], p1 = sm.pref[1];
            const int sp = 8 * (lvl + 1), sb = 8 * lvl;
            for (uint32_t i = tid; i < C; i += NTH) {
                uint32_t k = sm.keys[i], hi = k >> sp, by = (k >> sb) & 255u;
                if (!f0 && hi == p0) atomicAdd(&sm.h8[by], 1u);
                if (!f1 && hi == p1) atomicAdd(&sm.h8[HPAD + by], 1u);
            }
            __syncthreads();
            if (wv < 2 && !sm.flagAll[wv]) {
                uint32_t bsel, nr;
                binSelP(&sm.h8[wv * HPAD], 1, lane, sm.rank[wv], bsel, nr);
                if (lane == 0) { sm.pref[wv] = (sm.pref[wv] << 8) | bsel; sm.rank[wv] = nr; }
            }
            __syncthreads();
        }

        // collect strict winners, tie/sentinel pad
        if (tid < 2) sm.ccnt[tid] = 0u;
        __syncthreads();
        const int g0 = (ph == 0) ? 0 : 1;
        const int g1 = (ph == 0) ? 3 : 2;
        {
            int f0 = sm.flagAll[0], f1 = sm.flagAll[1];
            uint32_t t0 = sm.pref[0], t1 = sm.pref[1];
            for (uint32_t i = tid; i < C; i += NTH) {
                uint32_t k = sm.keys[i];
                if (f0 || k < t0) { uint32_t s = atomicAdd(&sm.ccnt[0], 1u); if (s < KPTS) sm.buf[g0][s] = key2f(k); }
                if (f1 || k > t1) { uint32_t s = atomicAdd(&sm.ccnt[1], 1u); if (s < KPTS) sm.buf[g1][s] = key2f(k); }
            }
        }
        __syncthreads();
        if (tid < 2 * KPTS) {
            int l = tid >> 7, i = tid & 127;
            int g = (l == 0) ? g0 : g1;
            if ((uint32_t)i >= sm.ccnt[l])
                sm.buf[g][i] = sm.flagAll[l] ? ((l == 0) ? BIGF : -BIGF) : key2f(sm.pref[l]);
        }
        __syncthreads();
    }

    // 4 register-resident 128-elem bitonic sorts (waves 0..3, no barriers)
    if (wv < 4) {
        float e[2];
        e[0] = sm.buf[wv][lane];
        e[1] = sm.buf[wv][lane + 64];
        waveSort128(e, wv < 2, lane);
        diagOut[(size_t)im * 512 + wv * 128 + lane]      = e[0];
        diagOut[(size_t)im * 512 + wv * 128 + 64 + lane] = e[1];
    }
}

// ---------------- loss + reduce ----------------
__global__ __launch_bounds__(128) void topo_loss_kernel(
        const float* __restrict__ diag, float* __restrict__ lossOut, int B) {
    const int s = blockIdx.x, i = threadIdx.x;
    const float* xw = diag + (size_t)(2 * s) * 512;
    const float* yw = xw + 512;
    const float H = 0.5f * BIGF;
    float b0x = xw[i], d0x = xw[128 + i], b1x = xw[256 + i], d1x = xw[384 + i];
    float b0y = yw[i], d0y = yw[128 + i], b1y = yw[256 + i], d1y = yw[384 + i];
    bool vx0 = (b0x < H) && (d0x < H);
    float px0b = vx0 ? b0x : 0.f, px0d = vx0 ? fmaxf(d0x, b0x) : 0.f;
    bool vy0 = (b0y < H) && (d0y < H);
    float py0b = vy0 ? b0y : 0.f, py0d = vy0 ? fmaxf(d0y, b0y) : 0.f;
    bool vx1 = (b1x > -H) && (d1x > -H);
    float px1b = vx1 ? b1x : 0.f, px1d = vx1 ? fminf(d1x, b1x) : 0.f;
    bool vy1 = (b1y > -H) && (d1y > -H);
    float py1b = vy1 ? b1y : 0.f, py1d = vy1 ? fminf(d1y, b1y) : 0.f;
    float e0 = px0b - py0b, e1 = px0d - py0d, e2 = px1b - py1b, e3 = px1d - py1d;
    float total = e0 * e0 + e1 * e1 + e2 * e2 + e3 * e3;
    for (int off = 32; off; off >>= 1) total += __shfl_down(total, off);
    __shared__ float lr[2];
    if ((i & 63) == 0) lr[i >> 6] = total;
    __syncthreads();
    if (i == 0) lossOut[s] = lr[0] + lr[1];
}

__global__ void topo_reduce_kernel(const float* __restrict__ ws, float* __restrict__ out, int B) {
    float v = 0.f;
    for (int i = threadIdx.x; i < B; i += 256) v += ws[i];
    __shared__ float r[4];
    for (int off = 32; off; off >>= 1) v += __shfl_down(v, off);
    if ((threadIdx.x & 63) == 0) r[threadIdx.x >> 6] = v;
    __syncthreads();
    if (threadIdx.x == 0) out[0] = (r[0] + r[1] + r[2] + r[3]) / (float)B;
}

// ================= fallback: fused pd3 kernel (round-8/9 proven) =================
template <bool WANTK>
__device__ __forceinline__ void stencilRow(const float* __restrict__ img, int row, int lane,
                                           bool mnf[4], bool mxf[4], uint32_t kk[4]) {
    const float* base = img + (size_t)row * IMG_W;
    float4 cur = *(const float4*)(base + lane * 4);
    bool hu = row > 0, hd = row < (IMG_W - 1);
    float4 up = cur, dn = cur;
    if (hu) up = *(const float4*)(base - IMG_W + lane * 4);
    if (hd) dn = *(const float4*)(base + IMG_W + lane * 4);
    float lft = __shfl_up(cur.w, 1);
    float rgt = __shfl_down(cur.x, 1);
    bool hl = (lane > 0), hr = (lane < 63);
    float cv[4] = {cur.x, cur.y, cur.z, cur.w};
    float uv[4] = {up.x, up.y, up.z, up.w};
    float dv[4] = {dn.x, dn.y, dn.z, dn.w};
    #pragma unroll
    for (int j = 0; j < 4; ++j) {
        float v = cv[j];
        bool el = (j > 0) || hl, er = (j < 3) || hr;
        float vl = (j > 0) ? cv[j - 1] : lft;
        float vr = (j < 3) ? cv[j + 1] : rgt;
        float nmn = fminf(fminf(el ? vl : BIGF, er ? vr : BIGF),
                          fminf(hu ? uv[j] : BIGF, hd ? dv[j] : BIGF));
        float nmx = fmaxf(fmaxf(el ? vl : -BIGF, er ? vr : -BIGF),
                          fmaxf(hu ? uv[j] : -BIGF, hd ? dv[j] : -BIGF));
        mnf[j] = (v <= nmn);
        mxf[j] = (v >= nmx);
        if (WANTK) kk[j] = f2key(cv[j]);
    }
}

struct SMP {
    uint32_t keys[LCAP];
    uint32_t h8[8][256];
    uint32_t cnt[2];
    uint32_t pref[2], rank[2], ccnt[2];
    int      flagAll[2];
    float    buf[4][KPTS];
};

__device__ __forceinline__ void binSelN(const uint32_t (*h)[256], int ncop, int lane, uint32_t r,
                                        uint32_t& bsel, uint32_t& newr) {
    uint32_t b0 = 0, b1 = 0, b2 = 0, b3 = 0;
    for (int c = 0; c < ncop; ++c) {
        b0 += h[c][4 * lane];     b1 += h[c][4 * lane + 1];
        b2 += h[c][4 * lane + 2]; b3 += h[c][4 * lane + 3];
    }
    uint32_t s4 = b0 + b1 + b2 + b3, cum = s4;
    #pragma unroll
    for (int d = 1; d < 64; d <<= 1) { uint32_t t = __shfl_up(cum, d); if (lane >= d) cum += t; }
    unsigned long long m = __ballot(cum > r);
    int L = (m == 0ull) ? 63 : __builtin_ctzll(m);
    uint32_t cumL = __shfl(cum, L), s4L = __shfl(s4, L);
    uint32_t a0 = __shfl(b0, L), a1 = __shfl(b1, L), a2 = __shfl(b2, L);
    uint32_t excl = cumL - s4L;
    if (excl + a0 > r)                { bsel = 4u * L;     newr = r - excl; }
    else if (excl + a0 + a1 > r)      { bsel = 4u * L + 1; newr = r - excl - a0; }
    else if (excl + a0 + a1 + a2 > r) { bsel = 4u * L + 2; newr = r - excl - a0 - a1; }
    else                              { bsel = 4u * L + 3; newr = r - excl - a0 - a1 - a2; }
}

__global__ __launch_bounds__(NTH, 8) void topo_pd3_kernel(
        const float* __restrict__ X, const float* __restrict__ Y,
        float* __restrict__ diagOut, int B) {
    __shared__ SMP sm;
    const int tid = threadIdx.x;
    const int lane = tid & 63;
    const int wv = tid >> 6;
    const int bid = blockIdx.x;
    const float* img = ((bid & 1) ? Y : X) + (size_t)(bid >> 1) * NPIX;
    const unsigned long long ltm = (1ull << lane) - 1ull;

    for (int ph = 0; ph < 2; ++ph) {
        for (int i = tid; i < 8 * 256; i += NTH) ((uint32_t*)sm.h8)[i] = 0u;
        if (tid == 0) sm.cnt[0] = 0u;
        __syncthreads();
        for (int it = 0; it < QITERS; ++it) {
            int q = it * NTH + tid;
            int p = q * 4;
            int row = p >> 8;
            bool mnf[4], mxf[4]; uint32_t kk[4];
            stencilRow<true>(img, row, lane, mnf, mxf, kk);
            bool e0 = (ph == 0) ? mnf[0] : mxf[0], e1 = (ph == 0) ? mnf[1] : mxf[1];
            bool e2 = (ph == 0) ? mnf[2] : mxf[2], e3 = (ph == 0) ? mnf[3] : mxf[3];
            unsigned long long m0 = __ballot(e0), m1 = __ballot(e1),
                               m2 = __ballot(e2), m3 = __ballot(e3);
            uint32_t c0 = (uint32_t)__popcll(m0), c1 = (uint32_t)__popcll(m1),
                     c2 = (uint32_t)__popcll(m2), c3 = (uint32_t)__popcll(m3);
            uint32_t base = 0;
            if (lane == 0) base = atomicAdd(&sm.cnt[0], c0 + c1 + c2 + c3);
            base = __shfl(base, 0);
            uint32_t o;
            if (e0) { o = base + (uint32_t)__popcll(m0 & ltm);                sm.keys[o < LCAP ? o : LCAP - 1] = kk[0]; atomicAdd(&sm.h8[wv >> 1][kk[0] >> 24], 1u); }
            if (e1) { o = base + c0 + (uint32_t)__popcll(m1 & ltm);           sm.keys[o < LCAP ? o : LCAP - 1] = kk[1]; atomicAdd(&sm.h8[wv >> 1][kk[1] >> 24], 1u); }
            if (e2) { o = base + c0 + c1 + (uint32_t)__popcll(m2 & ltm);      sm.keys[o < LCAP ? o : LCAP - 1] = kk[2]; atomicAdd(&sm.h8[wv >> 1][kk[2] >> 24], 1u); }
            if (e3) { o = base + c0 + c1 + c2 + (uint32_t)__popcll(m3 & ltm); sm.keys[o < LCAP ? o : LCAP - 1] = kk[3]; atomicAdd(&sm.h8[wv >> 1][kk[3] >> 24], 1u); }
        }
        __syncthreads();
        uint32_t C = sm.cnt[0]; if (C > LCAP) C = LCAP;

        if (wv < 2) {
            bool low = (wv == 0);
            if (C < KPTS) {
                if (lane == 0) { sm.flagAll[wv] = 1; sm.pref[wv] = 0u; sm.rank[wv] = 0u; }
            } else {
                uint32_t bsel, nr;
                binSelN(sm.h8, 8, lane, low ? (KPTS - 1) : (C - KPTS), bsel, nr);
                if (lane == 0) { sm.flagAll[wv] = 0; sm.pref[wv] = bsel; sm.rank[wv] = nr; }
            }
        }
        __syncthreads();

        for (int lvl = 2; lvl >= 0; --lvl) {
            for (int i = tid; i < 2 * 256; i += NTH) ((uint32_t*)sm.h8)[i] = 0u;
            __syncthreads();
            int f0 = sm.flagAll[0], f1 = sm.flagAll[1];
            uint32_t p0 = sm.pref[0], p1 = sm.pref[1];
            const int sp = 8 * (lvl + 1), sb = 8 * lvl;
            for (uint32_t i = tid; i < C; i += NTH) {
                uint32_t k = sm.keys[i], hi = k >> sp, by = (k >> sb) & 255u;
                if (!f0 && hi == p0) atomicAdd(&sm.h8[0][by], 1u);
                if (!f1 && hi == p1) atomicAdd(&sm.h8[1][by], 1u);
            }
            __syncthreads();
            if (wv < 2 && !sm.flagAll[wv]) {
                uint32_t bsel, nr;
                binSelN((const uint32_t(*)[256])&sm.h8[wv], 1, lane, sm.rank[wv], bsel, nr);
                if (lane == 0) { sm.pref[wv] = (sm.pref[wv] << 8) | bsel; sm.rank[wv] = nr; }
            }
            __syncthreads();
        }

        if (tid < 2) sm.ccnt[tid] = 0u;
        __syncthreads();
        const int g0 = (ph == 0) ? 0 : 1;
        const int g1 = (ph == 0) ? 3 : 2;
        {
            int f0 = sm.flagAll[0], f1 = sm.flagAll[1];
            uint32_t t0 = sm.pref[0], t1 = sm.pref[1];
            for (uint32_t i = tid; i < C; i += NTH) {
                uint32_t k = sm.keys[i];
                if (f0 || k < t0) { uint32_t q = atomicAdd(&sm.ccnt[0], 1u); if (q < KPTS) sm.buf[g0][q] = key2f(k); }
                if (f1 || k > t1) { uint32_t q = atomicAdd(&sm.ccnt[1], 1u); if (q < KPTS) sm.buf[g1][q] = key2f(k); }
            }
        }
        __syncthreads();
        if (tid < 2 * KPTS) {
            int l = tid >> 7, i = tid & 127;
            int g = (l == 0) ? g0 : g1;
            if ((uint32_t)i >= sm.ccnt[l])
                sm.buf[g][i] = sm.flagAll[l] ? ((l == 0) ? BIGF : -BIGF) : key2f(sm.pref[l]);
        }
        __syncthreads();
    }

    if (wv < 4) {
        float e[2];
        e[0] = sm.buf[wv][lane];
        e[1] = sm.buf[wv][lane + 64];
        waveSort128(e, wv < 2, lane);
        diagOut[(size_t)bid * 512 + wv * 128 + lane]      = e[0];
        diagOut[(size_t)bid * 512 + wv * 128 + 64 + lane] = e[1];
    }
}

extern "C" void kernel_launch(void* const* d_in, const int* in_sizes, int n_in,
                              void* d_out, int out_size, void* d_ws, size_t ws_size,
                              hipStream_t stream) {
    const float* X = (const float*)d_in[0];
    const float* Y = (const float*)d_in[1];
    float* out = (float*)d_out;
    const int B = in_sizes[0] / NPIX;   // 256 samples

    size_t diagSz = (size_t)2 * B * 512 * sizeof(float);              // 2 MB
    size_t lossSz = (size_t)B * sizeof(float);
    size_t cntSz  = (size_t)2 * B * 2 * 16 * sizeof(uint32_t);        // 64 KB
    size_t keysSz = (size_t)2 * B * 2 * LCAP * sizeof(uint32_t);      // 67 MB

    if (ws_size >= diagSz + lossSz + cntSz + keysSz) {
        float* diag = (float*)d_ws;
        float* lossbuf = (float*)((char*)d_ws + diagSz);
        uint32_t* gcnt16 = (uint32_t*)((char*)d_ws + diagSz + lossSz);
        uint32_t* gkeys = (uint32_t*)((char*)d_ws + diagSz + lossSz + cntSz);
        // no memset needed: every segment count is written unconditionally
        topo_scan7_kernel<<<8 * B, 256, 0, stream>>>(X, Y, gkeys, gcnt16, B);
        topo_sel2_kernel<<<2 * B, NTH, 0, stream>>>(gkeys, gcnt16, diag, B);
        topo_loss_kernel<<<B, 128, 0, stream>>>(diag, lossbuf, B);
        topo_reduce_kernel<<<1, 256, 0, stream>>>(lossbuf, out, B);
    } else if (ws_size >= diagSz + lossSz) {
        float* diag = (float*)d_ws;
        float* lossbuf = (float*)((char*)d_ws + diagSz);
        topo_pd3_kernel<<<2 * B, NTH, 0, stream>>>(X, Y, diag, B);
        topo_loss_kernel<<<B, 128, 0, stream>>>(diag, lossbuf, B);
        topo_reduce_kernel<<<1, 256, 0, stream>>>(lossbuf, out, B);
    } else {
        topo_pd3_kernel<<<2 * B, NTH, 0, stream>>>(X, Y, (float*)d_ws, B);
    }
}

// Round 19
// 90.085 us; speedup vs baseline: 1.3846x; 1.0579x over previous
//
#include <hip/hip_runtime.h>
#include <stdint.h>

// TopoLoss: approximate persistence-diagram Wasserstein loss.
// Round 19: REVERT to the proven best (round-15) pipeline: scan4 (combined-type
// rolling 3-row window, segmented zero-atomic output) + sel2 (per-image LDS
// radix-select, 2 blocks/CU) + loss + reduce = 90.3us measured. Rounds 16-18's
// scan experiments (type-split, deeper prefetch, fusion) all regressed; the
// scan is plateaued at ~62us on the ballot/scatter chain, not load latency.
// Order statistics bit-exact.

#define KPTS 128
#define BIGF 1.0e9f
#define IMG_W 256
#define NPIX (IMG_W * IMG_W)
#define NTH 1024
#define QITERS (NPIX / 4 / NTH)   // fallback kernel
#define SEGC 1024                 // per-wave segment capacity (E~819, sigma~26: +8sig)
#define LCAP (16 * SEGC)          // 16384 per image-type
#define HPAD 264                  // histogram copy stride (bank-skew: 264%32=8)

__device__ __forceinline__ uint32_t f2key(float f) {
    uint32_t u = __float_as_uint(f);
    return (u & 0x80000000u) ? ~u : (u | 0x80000000u);
}
__device__ __forceinline__ float key2f(uint32_t k) {
    uint32_t u = (k & 0x80000000u) ? (k ^ 0x80000000u) : ~k;
    return __uint_as_float(u);
}

// buf layout: 0=b0 (min,low,asc) 1=d0 (max,low,asc) 2=b1 (max,high,desc) 3=d1 (min,high,desc)

// ---------------- K1: combined-type scan, rolling 3-row window (r15 proven) ----------------
__global__ __launch_bounds__(256) void topo_scan4_kernel(
        const float* __restrict__ X, const float* __restrict__ Y,
        uint32_t* __restrict__ gkeys, uint32_t* __restrict__ gcnt16, int B) {
    const int tid = threadIdx.x;
    const int lane = tid & 63;
    const int wv = tid >> 6;
    const int gw = blockIdx.x * 4 + wv;      // 0..2B*16-1
    const int im = gw >> 4;                  // image id (16 waves/image)
    const int seg = gw & 15;
    const int r0 = seg * 16;
    const float* img = ((im & 1) ? Y : X) + (size_t)(im >> 1) * NPIX;
    const float* base0 = img + (size_t)r0 * IMG_W + lane * 4;
    const unsigned long long ltm = (1ull << lane) - 1ull;

    uint32_t* dMin = gkeys + (size_t)(im * 2 + 0) * LCAP + seg * SEGC;
    uint32_t* dMax = gkeys + (size_t)(im * 2 + 1) * LCAP + seg * SEGC;
    uint32_t cMin = 0, cMax = 0;

    // rolling 3-row window: prev = row r-1, cur = row r, next = row r+1
    float4 cur  = *(const float4*)(base0);
    float4 prev = (r0 > 0) ? *(const float4*)(base0 - IMG_W) : cur;   // consumed under hu guard
    float4 next = *(const float4*)(base0 + IMG_W);                    // r0+1 <= 241 < 256 always

    for (int it = 0; it < 16; ++it) {
        const int row = r0 + it;
        const bool hu = row > 0, hd = row < (IMG_W - 1);
        // prefetch row r+2 (next iteration's 'next') BEFORE the compute
        float4 nxt2 = cur;
        if (it < 15 && row + 2 < IMG_W)
            nxt2 = *(const float4*)(base0 + (it + 2) * IMG_W);

        float lft = __shfl_up(cur.w, 1);
        float rgt = __shfl_down(cur.x, 1);
        bool hl = (lane > 0), hr = (lane < 63);
        float cv[4] = {cur.x, cur.y, cur.z, cur.w};
        float uv[4] = {prev.x, prev.y, prev.z, prev.w};
        float dv[4] = {next.x, next.y, next.z, next.w};
        bool mnf[4], mxf[4];
        uint32_t kk[4];
        #pragma unroll
        for (int j = 0; j < 4; ++j) {
            float v = cv[j];
            bool el = (j > 0) || hl, er = (j < 3) || hr;
            float vl = (j > 0) ? cv[j - 1] : lft;
            float vr = (j < 3) ? cv[j + 1] : rgt;
            float nmn = fminf(fminf(el ? vl : BIGF, er ? vr : BIGF),
                              fminf(hu ? uv[j] : BIGF, hd ? dv[j] : BIGF));
            float nmx = fmaxf(fmaxf(el ? vl : -BIGF, er ? vr : -BIGF),
                              fmaxf(hu ? uv[j] : -BIGF, hd ? dv[j] : -BIGF));
            mnf[j] = (v <= nmn);
            mxf[j] = (v >= nmx);
            kk[j] = f2key(v);
        }
        {
            unsigned long long m0 = __ballot(mnf[0]), m1 = __ballot(mnf[1]),
                               m2 = __ballot(mnf[2]), m3 = __ballot(mnf[3]);
            uint32_t c0 = (uint32_t)__popcll(m0), c1 = (uint32_t)__popcll(m1),
                     c2 = (uint32_t)__popcll(m2), c3 = (uint32_t)__popcll(m3);
            uint32_t o;
            if (mnf[0]) { o = cMin + (uint32_t)__popcll(m0 & ltm);                if (o < SEGC) dMin[o] = kk[0]; }
            if (mnf[1]) { o = cMin + c0 + (uint32_t)__popcll(m1 & ltm);           if (o < SEGC) dMin[o] = kk[1]; }
            if (mnf[2]) { o = cMin + c0 + c1 + (uint32_t)__popcll(m2 & ltm);      if (o < SEGC) dMin[o] = kk[2]; }
            if (mnf[3]) { o = cMin + c0 + c1 + c2 + (uint32_t)__popcll(m3 & ltm); if (o < SEGC) dMin[o] = kk[3]; }
            cMin += c0 + c1 + c2 + c3;
        }
        {
            unsigned long long m0 = __ballot(mxf[0]), m1 = __ballot(mxf[1]),
                               m2 = __ballot(mxf[2]), m3 = __ballot(mxf[3]);
            uint32_t c0 = (uint32_t)__popcll(m0), c1 = (uint32_t)__popcll(m1),
                     c2 = (uint32_t)__popcll(m2), c3 = (uint32_t)__popcll(m3);
            uint32_t o;
            if (mxf[0]) { o = cMax + (uint32_t)__popcll(m0 & ltm);                if (o < SEGC) dMax[o] = kk[0]; }
            if (mxf[1]) { o = cMax + c0 + (uint32_t)__popcll(m1 & ltm);           if (o < SEGC) dMax[o] = kk[1]; }
            if (mxf[2]) { o = cMax + c0 + c1 + (uint32_t)__popcll(m2 & ltm);      if (o < SEGC) dMax[o] = kk[2]; }
            if (mxf[3]) { o = cMax + c0 + c1 + c2 + (uint32_t)__popcll(m3 & ltm); if (o < SEGC) dMax[o] = kk[3]; }
            cMax += c0 + c1 + c2 + c3;
        }
        prev = cur; cur = next; next = nxt2;   // slide the window
    }
    if (lane == 0) {
        gcnt16[(im * 2 + 0) * 16 + seg] = (cMin < SEGC) ? cMin : SEGC;
        gcnt16[(im * 2 + 1) * 16 + seg] = (cMax < SEGC) ? cMax : SEGC;
    }
}

// ---------------- K2: per-image segment-compacting radix select + register sort ----------------
struct SMQ {
    uint32_t keys[LCAP];      // 64 KB
    uint32_t h8[8 * HPAD];    // 8.25 KB (skewed copies)
    uint32_t pref[2], rank[2], ccnt[2];
    int      flagAll[2];
    float    buf[4][KPTS];    // 2 KB
};                            // ~74.5 KB -> 2 blocks/CU

__device__ __forceinline__ void binSelP(const uint32_t* h, int ncop, int lane, uint32_t r,
                                        uint32_t& bsel, uint32_t& newr) {
    uint32_t b0 = 0, b1 = 0, b2 = 0, b3 = 0;
    for (int c = 0; c < ncop; ++c) {
        const uint32_t* hh = h + c * HPAD;
        b0 += hh[4 * lane];     b1 += hh[4 * lane + 1];
        b2 += hh[4 * lane + 2]; b3 += hh[4 * lane + 3];
    }
    uint32_t s4 = b0 + b1 + b2 + b3, cum = s4;
    #pragma unroll
    for (int d = 1; d < 64; d <<= 1) { uint32_t t = __shfl_up(cum, d); if (lane >= d) cum += t; }
    unsigned long long m = __ballot(cum > r);
    int L = (m == 0ull) ? 63 : __builtin_ctzll(m);
    uint32_t cumL = __shfl(cum, L), s4L = __shfl(s4, L);
    uint32_t a0 = __shfl(b0, L), a1 = __shfl(b1, L), a2 = __shfl(b2, L);
    uint32_t excl = cumL - s4L;
    if (excl + a0 > r)                { bsel = 4u * L;     newr = r - excl; }
    else if (excl + a0 + a1 > r)      { bsel = 4u * L + 1; newr = r - excl - a0; }
    else if (excl + a0 + a1 + a2 > r) { bsel = 4u * L + 2; newr = r - excl - a0 - a1; }
    else                              { bsel = 4u * L + 3; newr = r - excl - a0 - a1 - a2; }
}

// 128-element bitonic sort in registers, one wave, 2 elems/lane.
__device__ __forceinline__ void waveSort128(float e[2], bool asc, int lane) {
    for (int size = 2; size <= 128; size <<= 1) {
        for (int stride = size >> 1; stride > 0; stride >>= 1) {
            if (stride == 64) {
                float a = e[0], b = e[1];
                e[0] = asc ? fminf(a, b) : fmaxf(a, b);
                e[1] = asc ? fmaxf(a, b) : fminf(a, b);
            } else {
                #pragma unroll
                for (int r = 0; r < 2; ++r) {
                    int i = r * 64 + lane;
                    float v = e[r];
                    float w = __shfl_xor(v, stride);
                    bool up = ((i & size) == 0) ? asc : !asc;
                    bool lower = (i & stride) == 0;
                    float mn = fminf(v, w), mx = fmaxf(v, w);
                    e[r] = (lower == up) ? mn : mx;
                }
            }
        }
    }
}

__global__ __launch_bounds__(NTH, 8) void topo_sel2_kernel(
        const uint32_t* __restrict__ gkeys, const uint32_t* __restrict__ gcnt16,
        float* __restrict__ diagOut, int B) {
    __shared__ SMQ sm;
    const int tid = threadIdx.x;
    const int lane = tid & 63;
    const int wv = tid >> 6;        // 16 waves
    const int im = blockIdx.x;
    const int hc = lane & 7;

    for (int ph = 0; ph < 2; ++ph) {   // 0: minima -> {b0,d1}; 1: maxima -> {d0,b1}
        for (int i = tid; i < 8 * HPAD; i += NTH) sm.h8[i] = 0u;
        __syncthreads();
        const uint32_t* list = gkeys + (size_t)(im * 2 + ph) * LCAP;
        const uint32_t* cnts = gcnt16 + (im * 2 + ph) * 16;

        // every wave: read 16 segment counts, shfl prefix scan -> my offset / total
        uint32_t cw = (lane < 16) ? cnts[lane] : 0;
        uint32_t inc = cw;
        #pragma unroll
        for (int d = 1; d < 16; d <<= 1) { uint32_t t = __shfl_up(inc, d); if (lane >= d) inc += t; }
        uint32_t C = __shfl(inc, 15);                 // total count
        uint32_t myCnt = __shfl(cw, wv);              // my segment's count
        uint32_t myOff = __shfl(inc, wv) - myCnt;     // exclusive prefix

        // wave wv compacts segment wv into LDS (+ lane-privatized skewed MSB hist)
        for (uint32_t i = lane; i < myCnt; i += 64) {
            uint32_t k = list[wv * SEGC + i];
            sm.keys[myOff + i] = k;
            atomicAdd(&sm.h8[hc * HPAD + (k >> 24)], 1u);
        }
        __syncthreads();

        // top-level select: wave0 = low sel, wave1 = high sel
        if (wv < 2) {
            bool low = (wv == 0);
            if (C < KPTS) {
                if (lane == 0) { sm.flagAll[wv] = 1; sm.pref[wv] = 0u; sm.rank[wv] = 0u; }
            } else {
                uint32_t bsel, nr;
                binSelP(sm.h8, 8, lane, low ? (KPTS - 1) : (C - KPTS), bsel, nr);
                if (lane == 0) { sm.flagAll[wv] = 0; sm.pref[wv] = bsel; sm.rank[wv] = nr; }
            }
        }
        __syncthreads();

        // levels 2..0: prefix-filtered LDS list scans
        for (int lvl = 2; lvl >= 0; --lvl) {
            for (int i = tid; i < 2 * HPAD; i += NTH) sm.h8[i] = 0u;
            __syncthreads();
            int f0 = sm.flagAll[0], f1 = sm.flagAll[1];
            uint32_t p0 = sm.pref[0], p1 = sm.pref[1];
            const int sp = 8 * (lvl + 1), sb = 8 * lvl;
            for (uint32_t i = tid; i < C; i += NTH) {
                uint32_t k = sm.keys[i], hi = k >> sp, by = (k >> sb) & 255u;
                if (!f0 && hi == p0) atomicAdd(&sm.h8[by], 1u);
                if (!f1 && hi == p1) atomicAdd(&sm.h8[HPAD + by], 1u);
            }
            __syncthreads();
            if (wv < 2 && !sm.flagAll[wv]) {
                uint32_t bsel, nr;
                binSelP(&sm.h8[wv * HPAD], 1, lane, sm.rank[wv], bsel, nr);
                if (lane == 0) { sm.pref[wv] = (sm.pref[wv] << 8) | bsel; sm.rank[wv] = nr; }
            }
            __syncthreads();
        }

        // collect strict winners, tie/sentinel pad
        if (tid < 2) sm.ccnt[tid] = 0u;
        __syncthreads();
        const int g0 = (ph == 0) ? 0 : 1;
        const int g1 = (ph == 0) ? 3 : 2;
        {
            int f0 = sm.flagAll[0], f1 = sm.flagAll[1];
            uint32_t t0 = sm.pref[0], t1 = sm.pref[1];
            for (uint32_t i = tid; i < C; i += NTH) {
                uint32_t k = sm.keys[i];
                if (f0 || k < t0) { uint32_t s = atomicAdd(&sm.ccnt[0], 1u); if (s < KPTS) sm.buf[g0][s] = key2f(k); }
                if (f1 || k > t1) { uint32_t s = atomicAdd(&sm.ccnt[1], 1u); if (s < KPTS) sm.buf[g1][s] = key2f(k); }
            }
        }
        __syncthreads();
        if (tid < 2 * KPTS) {
            int l = tid >> 7, i = tid & 127;
            int g = (l == 0) ? g0 : g1;
            if ((uint32_t)i >= sm.ccnt[l])
                sm.buf[g][i] = sm.flagAll[l] ? ((l == 0) ? BIGF : -BIGF) : key2f(sm.pref[l]);
        }
        __syncthreads();
    }

    // 4 register-resident 128-elem bitonic sorts (waves 0..3, no barriers)
    if (wv < 4) {
        float e[2];
        e[0] = sm.buf[wv][lane];
        e[1] = sm.buf[wv][lane + 64];
        waveSort128(e, wv < 2, lane);
        diagOut[(size_t)im * 512 + wv * 128 + lane]      = e[0];
        diagOut[(size_t)im * 512 + wv * 128 + 64 + lane] = e[1];
    }
}

// ---------------- loss + reduce ----------------
__global__ __launch_bounds__(128) void topo_loss_kernel(
        const float* __restrict__ diag, float* __restrict__ lossOut, int B) {
    const int s = blockIdx.x, i = threadIdx.x;
    const float* xw = diag + (size_t)(2 * s) * 512;
    const float* yw = xw + 512;
    const float H = 0.5f * BIGF;
    float b0x = xw[i], d0x = xw[128 + i], b1x = xw[256 + i], d1x = xw[384 + i];
    float b0y = yw[i], d0y = yw[128 + i], b1y = yw[256 + i], d1y = yw[384 + i];
    bool vx0 = (b0x < H) && (d0x < H);
    float px0b = vx0 ? b0x : 0.f, px0d = vx0 ? fmaxf(d0x, b0x) : 0.f;
    bool vy0 = (b0y < H) && (d0y < H);
    float py0b = vy0 ? b0y : 0.f, py0d = vy0 ? fmaxf(d0y, b0y) : 0.f;
    bool vx1 = (b1x > -H) && (d1x > -H);
    float px1b = vx1 ? b1x : 0.f, px1d = vx1 ? fminf(d1x, b1x) : 0.f;
    bool vy1 = (b1y > -H) && (d1y > -H);
    float py1b = vy1 ? b1y : 0.f, py1d = vy1 ? fminf(d1y, b1y) : 0.f;
    float e0 = px0b - py0b, e1 = px0d - py0d, e2 = px1b - py1b, e3 = px1d - py1d;
    float total = e0 * e0 + e1 * e1 + e2 * e2 + e3 * e3;
    for (int off = 32; off; off >>= 1) total += __shfl_down(total, off);
    __shared__ float lr[2];
    if ((i & 63) == 0) lr[i >> 6] = total;
    __syncthreads();
    if (i == 0) lossOut[s] = lr[0] + lr[1];
}

__global__ void topo_reduce_kernel(const float* __restrict__ ws, float* __restrict__ out, int B) {
    float v = 0.f;
    for (int i = threadIdx.x; i < B; i += 256) v += ws[i];
    __shared__ float r[4];
    for (int off = 32; off; off >>= 1) v += __shfl_down(v, off);
    if ((threadIdx.x & 63) == 0) r[threadIdx.x >> 6] = v;
    __syncthreads();
    if (threadIdx.x == 0) out[0] = (r[0] + r[1] + r[2] + r[3]) / (float)B;
}

// ================= fallback: fused pd3 kernel (round-8/9 proven) =================
template <bool WANTK>
__device__ __forceinline__ void stencilRow(const float* __restrict__ img, int row, int lane,
                                           bool mnf[4], bool mxf[4], uint32_t kk[4]) {
    const float* base = img + (size_t)row * IMG_W;
    float4 cur = *(const float4*)(base + lane * 4);
    bool hu = row > 0, hd = row < (IMG_W - 1);
    float4 up = cur, dn = cur;
    if (hu) up = *(const float4*)(base - IMG_W + lane * 4);
    if (hd) dn = *(const float4*)(base + IMG_W + lane * 4);
    float lft = __shfl_up(cur.w, 1);
    float rgt = __shfl_down(cur.x, 1);
    bool hl = (lane > 0), hr = (lane < 63);
    float cv[4] = {cur.x, cur.y, cur.z, cur.w};
    float uv[4] = {up.x, up.y, up.z, up.w};
    float dv[4] = {dn.x, dn.y, dn.z, dn.w};
    #pragma unroll
    for (int j = 0; j < 4; ++j) {
        float v = cv[j];
        bool el = (j > 0) || hl, er = (j < 3) || hr;
        float vl = (j > 0) ? cv[j - 1] : lft;
        float vr = (j < 3) ? cv[j + 1] : rgt;
        float nmn = fminf(fminf(el ? vl : BIGF, er ? vr : BIGF),
                          fminf(hu ? uv[j] : BIGF, hd ? dv[j] : BIGF));
        float nmx = fmaxf(fmaxf(el ? vl : -BIGF, er ? vr : -BIGF),
                          fmaxf(hu ? uv[j] : -BIGF, hd ? dv[j] : -BIGF));
        mnf[j] = (v <= nmn);
        mxf[j] = (v >= nmx);
        if (WANTK) kk[j] = f2key(cv[j]);
    }
}

struct SMP {
    uint32_t keys[LCAP];
    uint32_t h8[8][256];
    uint32_t cnt[2];
    uint32_t pref[2], rank[2], ccnt[2];
    int      flagAll[2];
    float    buf[4][KPTS];
};

__device__ __forceinline__ void binSelN(const uint32_t (*h)[256], int ncop, int lane, uint32_t r,
                                        uint32_t& bsel, uint32_t& newr) {
    uint32_t b0 = 0, b1 = 0, b2 = 0, b3 = 0;
    for (int c = 0; c < ncop; ++c) {
        b0 += h[c][4 * lane];     b1 += h[c][4 * lane + 1];
        b2 += h[c][4 * lane + 2]; b3 += h[c][4 * lane + 3];
    }
    uint32_t s4 = b0 + b1 + b2 + b3, cum = s4;
    #pragma unroll
    for (int d = 1; d < 64; d <<= 1) { uint32_t t = __shfl_up(cum, d); if (lane >= d) cum += t; }
    unsigned long long m = __ballot(cum > r);
    int L = (m == 0ull) ? 63 : __builtin_ctzll(m);
    uint32_t cumL = __shfl(cum, L), s4L = __shfl(s4, L);
    uint32_t a0 = __shfl(b0, L), a1 = __shfl(b1, L), a2 = __shfl(b2, L);
    uint32_t excl = cumL - s4L;
    if (excl + a0 > r)                { bsel = 4u * L;     newr = r - excl; }
    else if (excl + a0 + a1 > r)      { bsel = 4u * L + 1; newr = r - excl - a0; }
    else if (excl + a0 + a1 + a2 > r) { bsel = 4u * L + 2; newr = r - excl - a0 - a1; }
    else                              { bsel = 4u * L + 3; newr = r - excl - a0 - a1 - a2; }
}

__global__ __launch_bounds__(NTH, 8) void topo_pd3_kernel(
        const float* __restrict__ X, const float* __restrict__ Y,
        float* __restrict__ diagOut, int B) {
    __shared__ SMP sm;
    const int tid = threadIdx.x;
    const int lane = tid & 63;
    const int wv = tid >> 6;
    const int bid = blockIdx.x;
    const float* img = ((bid & 1) ? Y : X) + (size_t)(bid >> 1) * NPIX;
    const unsigned long long ltm = (1ull << lane) - 1ull;

    for (int ph = 0; ph < 2; ++ph) {
        for (int i = tid; i < 8 * 256; i += NTH) ((uint32_t*)sm.h8)[i] = 0u;
        if (tid == 0) sm.cnt[0] = 0u;
        __syncthreads();
        for (int it = 0; it < QITERS; ++it) {
            int q = it * NTH + tid;
            int p = q * 4;
            int row = p >> 8;
            bool mnf[4], mxf[4]; uint32_t kk[4];
            stencilRow<true>(img, row, lane, mnf, mxf, kk);
            bool e0 = (ph == 0) ? mnf[0] : mxf[0], e1 = (ph == 0) ? mnf[1] : mxf[1];
            bool e2 = (ph == 0) ? mnf[2] : mxf[2], e3 = (ph == 0) ? mnf[3] : mxf[3];
            unsigned long long m0 = __ballot(e0), m1 = __ballot(e1),
                               m2 = __ballot(e2), m3 = __ballot(e3);
            uint32_t c0 = (uint32_t)__popcll(m0), c1 = (uint32_t)__popcll(m1),
                     c2 = (uint32_t)__popcll(m2), c3 = (uint32_t)__popcll(m3);
            uint32_t base = 0;
            if (lane == 0) base = atomicAdd(&sm.cnt[0], c0 + c1 + c2 + c3);
            base = __shfl(base, 0);
            uint32_t o;
            if (e0) { o = base + (uint32_t)__popcll(m0 & ltm);                sm.keys[o < LCAP ? o : LCAP - 1] = kk[0]; atomicAdd(&sm.h8[wv >> 1][kk[0] >> 24], 1u); }
            if (e1) { o = base + c0 + (uint32_t)__popcll(m1 & ltm);           sm.keys[o < LCAP ? o : LCAP - 1] = kk[1]; atomicAdd(&sm.h8[wv >> 1][kk[1] >> 24], 1u); }
            if (e2) { o = base + c0 + c1 + (uint32_t)__popcll(m2 & ltm);      sm.keys[o < LCAP ? o : LCAP - 1] = kk[2]; atomicAdd(&sm.h8[wv >> 1][kk[2] >> 24], 1u); }
            if (e3) { o = base + c0 + c1 + c2 + (uint32_t)__popcll(m3 & ltm); sm.keys[o < LCAP ? o : LCAP - 1] = kk[3]; atomicAdd(&sm.h8[wv >> 1][kk[3] >> 24], 1u); }
        }
        __syncthreads();
        uint32_t C = sm.cnt[0]; if (C > LCAP) C = LCAP;

        if (wv < 2) {
            bool low = (wv == 0);
            if (C < KPTS) {
                if (lane == 0) { sm.flagAll[wv] = 1; sm.pref[wv] = 0u; sm.rank[wv] = 0u; }
            } else {
                uint32_t bsel, nr;
                binSelN(sm.h8, 8, lane, low ? (KPTS - 1) : (C - KPTS), bsel, nr);
                if (lane == 0) { sm.flagAll[wv] = 0; sm.pref[wv] = bsel; sm.rank[wv] = nr; }
            }
        }
        __syncthreads();

        for (int lvl = 2; lvl >= 0; --lvl) {
            for (int i = tid; i < 2 * 256; i += NTH) ((uint32_t*)sm.h8)[i] = 0u;
            __syncthreads();
            int f0 = sm.flagAll[0], f1 = sm.flagAll[1];
            uint32_t p0 = sm.pref[0], p1 = sm.pref[1];
            const int sp = 8 * (lvl + 1), sb = 8 * lvl;
            for (uint32_t i = tid; i < C; i += NTH) {
                uint32_t k = sm.keys[i], hi = k >> sp, by = (k >> sb) & 255u;
                if (!f0 && hi == p0) atomicAdd(&sm.h8[0][by], 1u);
                if (!f1 && hi == p1) atomicAdd(&sm.h8[1][by], 1u);
            }
            __syncthreads();
            if (wv < 2 && !sm.flagAll[wv]) {
                uint32_t bsel, nr;
                binSelN((const uint32_t(*)[256])&sm.h8[wv], 1, lane, sm.rank[wv], bsel, nr);
                if (lane == 0) { sm.pref[wv] = (sm.pref[wv] << 8) | bsel; sm.rank[wv] = nr; }
            }
            __syncthreads();
        }

        if (tid < 2) sm.ccnt[tid] = 0u;
        __syncthreads();
        const int g0 = (ph == 0) ? 0 : 1;
        const int g1 = (ph == 0) ? 3 : 2;
        {
            int f0 = sm.flagAll[0], f1 = sm.flagAll[1];
            uint32_t t0 = sm.pref[0], t1 = sm.pref[1];
            for (uint32_t i = tid; i < C; i += NTH) {
                uint32_t k = sm.keys[i];
                if (f0 || k < t0) { uint32_t q = atomicAdd(&sm.ccnt[0], 1u); if (q < KPTS) sm.buf[g0][q] = key2f(k); }
                if (f1 || k > t1) { uint32_t q = atomicAdd(&sm.ccnt[1], 1u); if (q < KPTS) sm.buf[g1][q] = key2f(k); }
            }
        }
        __syncthreads();
        if (tid < 2 * KPTS) {
            int l = tid >> 7, i = tid & 127;
            int g = (l == 0) ? g0 : g1;
            if ((uint32_t)i >= sm.ccnt[l])
                sm.buf[g][i] = sm.flagAll[l] ? ((l == 0) ? BIGF : -BIGF) : key2f(sm.pref[l]);
        }
        __syncthreads();
    }

    if (wv < 4) {
        float e[2];
        e[0] = sm.buf[wv][lane];
        e[1] = sm.buf[wv][lane + 64];
        waveSort128(e, wv < 2, lane);
        diagOut[(size_t)bid * 512 + wv * 128 + lane]      = e[0];
        diagOut[(size_t)bid * 512 + wv * 128 + 64 + lane] = e[1];
    }
}

extern "C" void kernel_launch(void* const* d_in, const int* in_sizes, int n_in,
                              void* d_out, int out_size, void* d_ws, size_t ws_size,
                              hipStream_t stream) {
    const float* X = (const float*)d_in[0];
    const float* Y = (const float*)d_in[1];
    float* out = (float*)d_out;
    const int B = in_sizes[0] / NPIX;   // 256 samples

    size_t diagSz = (size_t)2 * B * 512 * sizeof(float);              // 2 MB
    size_t lossSz = (size_t)B * sizeof(float);
    size_t cntSz  = (size_t)2 * B * 2 * 16 * sizeof(uint32_t);        // 64 KB
    size_t keysSz = (size_t)2 * B * 2 * LCAP * sizeof(uint32_t);      // 67 MB

    if (ws_size >= diagSz + lossSz + cntSz + keysSz) {
        float* diag = (float*)d_ws;
        float* lossbuf = (float*)((char*)d_ws + diagSz);
        uint32_t* gcnt16 = (uint32_t*)((char*)d_ws + diagSz + lossSz);
        uint32_t* gkeys = (uint32_t*)((char*)d_ws + diagSz + lossSz + cntSz);
        // no memset needed: every segment count is written unconditionally
        topo_scan4_kernel<<<8 * B, 256, 0, stream>>>(X, Y, gkeys, gcnt16, B);
        topo_sel2_kernel<<<2 * B, NTH, 0, stream>>>(gkeys, gcnt16, diag, B);
        topo_loss_kernel<<<B, 128, 0, stream>>>(diag, lossbuf, B);
        topo_reduce_kernel<<<1, 256, 0, stream>>>(lossbuf, out, B);
    } else if (ws_size >= diagSz + lossSz) {
        float* diag = (float*)d_ws;
        float* lossbuf = (float*)((char*)d_ws + diagSz);
        topo_pd3_kernel<<<2 * B, NTH, 0, stream>>>(X, Y, diag, B);
        topo_loss_kernel<<<B, 128, 0, stream>>>(diag, lossbuf, B);
        topo_reduce_kernel<<<1, 256, 0, stream>>>(lossbuf, out, B);
    } else {
        topo_pd3_kernel<<<2 * B, NTH, 0, stream>>>(X, Y, (float*)d_ws, B);
    }
}